// Round 7
// baseline (254.746 us; speedup 1.0000x reference)
//
#include <hip/hip_runtime.h>

typedef __attribute__((ext_vector_type(8))) short short8;
typedef __attribute__((ext_vector_type(4))) float f32x4;

#define B_SZ 32
#define C_IN 512
#define C8V 64
#define LSEQ 1024
#define OUT_ELEMS (B_SZ * C_IN * LSEQ)

__device__ inline unsigned short bf16_rn(float f) {
  unsigned int u = __float_as_uint(f);
  unsigned int r = 0x7FFFu + ((u >> 16) & 1u);
  return (unsigned short)((u + r) >> 16);
}
__device__ inline float bf16_to_f32(unsigned short h) {
  return __uint_as_float(((unsigned int)h) << 16);
}
__device__ inline void split_bf16(float f, unsigned short &hi, unsigned short &lo) {
  hi = bf16_rn(f);
  lo = bf16_rn(f - bf16_to_f32(hi));
}

// ---------- Kernel 0: pre-split weights into bf16 hi/lo planes ----------
__global__ __launch_bounds__(256) void split_weights(
    const float* __restrict__ Wq, const float* __restrict__ Wk, const float* __restrict__ Wv,
    unsigned short* __restrict__ Wqh, unsigned short* __restrict__ Wql,
    unsigned short* __restrict__ Wkh, unsigned short* __restrict__ Wkl,
    unsigned short* __restrict__ Wvh)
{
  int i = (blockIdx.x * 256 + threadIdx.x) * 4;
  if (i < 262144) {
    f32x4 f = *(const f32x4*)&Wv[i];
    #pragma unroll
    for (int j = 0; j < 4; ++j) Wvh[i + j] = bf16_rn(f[j]);
  } else if (i < 294912) {
    int k = i - 262144;
    f32x4 f = *(const f32x4*)&Wq[k];
    #pragma unroll
    for (int j = 0; j < 4; ++j) { unsigned short h, l; split_bf16(f[j], h, l); Wqh[k+j] = h; Wql[k+j] = l; }
  } else {
    int k = i - 294912;
    f32x4 f = *(const f32x4*)&Wk[k];
    #pragma unroll
    for (int j = 0; j < 4; ++j) { unsigned short h, l; split_bf16(f[j], h, l); Wkh[k+j] = h; Wkl[k+j] = l; }
  }
}

// ---------- Kernel T: x [b][c][l] f32 -> xT hi/lo [b][l][c] bf16 ----------
__global__ __launch_bounds__(256) void transpose_split(
    const float* __restrict__ x,
    unsigned short* __restrict__ xth, unsigned short* __restrict__ xtl)
{
  const int lt = blockIdx.x, ct = blockIdx.y, b = blockIdx.z;
  const int tid = threadIdx.x;
  __shared__ float xs[64 * 68];

  #pragma unroll
  for (int i = 0; i < 4; ++i) {
    int idx = tid + i * 256;
    int c = idx >> 4, l4 = idx & 15;
    f32x4 v = *(const f32x4*)&x[((long)b*C_IN + ct*64 + c)*LSEQ + lt*64 + l4*4];
    *(f32x4*)&xs[c*68 + l4*4] = v;
  }
  __syncthreads();
  const int l = tid >> 2, seg = tid & 3;
  unsigned short hbuf[16], lbuf[16];
  #pragma unroll
  for (int i = 0; i < 16; ++i)
    split_bf16(xs[(seg*16 + i)*68 + l], hbuf[i], lbuf[i]);
  long base = ((long)b*LSEQ + lt*64 + l)*C_IN + ct*64 + seg*16;
  *(short8*)&xth[base]     = *(const short8*)&hbuf[0];
  *(short8*)&xth[base + 8] = *(const short8*)&hbuf[8];
  *(short8*)&xtl[base]     = *(const short8*)&lbuf[0];
  *(short8*)&xtl[base + 8] = *(const short8*)&lbuf[8];
}

// ---------- Kernel 1: q,k projection (pure bf16 GEMM) ----------
__global__ __launch_bounds__(256, 2) void qk_proj(
    const unsigned short* __restrict__ xth, const unsigned short* __restrict__ xtl,
    const unsigned short* __restrict__ Wqh, const unsigned short* __restrict__ Wql,
    const unsigned short* __restrict__ Wkh, const unsigned short* __restrict__ Wkl,
    const float* __restrict__ bq, const float* __restrict__ bk,
    unsigned short* __restrict__ qh, unsigned short* __restrict__ ql,
    unsigned short* __restrict__ kh, unsigned short* __restrict__ kl)
{
  const int nt = blockIdx.x;
  const int b  = blockIdx.y;
  const int tid = threadIdx.x;
  const int wave = tid >> 6, lane = tid & 63;
  const int wr = wave >> 1, wc = wave & 1;
  const int g = lane >> 4, ln = lane & 15;

  __shared__ char smem[49152];
  unsigned short* Ah = (unsigned short*)smem;      // [128][64] swizzled
  unsigned short* Al = Ah + 8192;
  unsigned short* Bh = Al + 8192;                  // [64][64] swizzled
  unsigned short* Bl = Bh + 4096;

  const int rb = tid >> 3, jj = tid & 7;
  const int dst0 = rb*64 + ((jj ^ (rb & 7)) << 3);
  const long xbase = ((long)b*LSEQ + nt*64 + rb)*C_IN + jj*8;

  short8 rAh[4], rAl[4], rBh[2], rBl[2];
  rAh[0] = *(const short8*)&Wqh[rb*C_IN + jj*8];
  rAh[1] = *(const short8*)&Wqh[(rb+32)*C_IN + jj*8];
  rAh[2] = *(const short8*)&Wkh[rb*C_IN + jj*8];
  rAh[3] = *(const short8*)&Wkh[(rb+32)*C_IN + jj*8];
  rAl[0] = *(const short8*)&Wql[rb*C_IN + jj*8];
  rAl[1] = *(const short8*)&Wql[(rb+32)*C_IN + jj*8];
  rAl[2] = *(const short8*)&Wkl[rb*C_IN + jj*8];
  rAl[3] = *(const short8*)&Wkl[(rb+32)*C_IN + jj*8];
  rBh[0] = *(const short8*)&xth[xbase];
  rBh[1] = *(const short8*)&xth[xbase + 32*C_IN];
  rBl[0] = *(const short8*)&xtl[xbase];
  rBl[1] = *(const short8*)&xtl[xbase + 32*C_IN];

  f32x4 acc[4][2] = {};

  for (int kb = 0; kb < 8; ++kb) {
    __syncthreads();
    #pragma unroll
    for (int j = 0; j < 4; ++j) {
      *(short8*)&Ah[dst0 + j*2048] = rAh[j];
      *(short8*)&Al[dst0 + j*2048] = rAl[j];
    }
    #pragma unroll
    for (int j = 0; j < 2; ++j) {
      *(short8*)&Bh[dst0 + j*2048] = rBh[j];
      *(short8*)&Bl[dst0 + j*2048] = rBl[j];
    }
    __syncthreads();
    if (kb < 7) {
      int ko = (kb+1)*64;
      rAh[0] = *(const short8*)&Wqh[rb*C_IN + ko + jj*8];
      rAh[1] = *(const short8*)&Wqh[(rb+32)*C_IN + ko + jj*8];
      rAh[2] = *(const short8*)&Wkh[rb*C_IN + ko + jj*8];
      rAh[3] = *(const short8*)&Wkh[(rb+32)*C_IN + ko + jj*8];
      rAl[0] = *(const short8*)&Wql[rb*C_IN + ko + jj*8];
      rAl[1] = *(const short8*)&Wql[(rb+32)*C_IN + ko + jj*8];
      rAl[2] = *(const short8*)&Wkl[rb*C_IN + ko + jj*8];
      rAl[3] = *(const short8*)&Wkl[(rb+32)*C_IN + ko + jj*8];
      rBh[0] = *(const short8*)&xth[xbase + ko];
      rBh[1] = *(const short8*)&xth[xbase + 32*C_IN + ko];
      rBl[0] = *(const short8*)&xtl[xbase + ko];
      rBl[1] = *(const short8*)&xtl[xbase + 32*C_IN + ko];
    }
    #pragma unroll
    for (int ks = 0; ks < 2; ++ks) {
      int s = ((ks*4 + g) ^ (ln & 7)) << 3;
      short8 bhf[2], blf[2];
      #pragma unroll
      for (int ni = 0; ni < 2; ++ni) {
        int cr = wc*32 + ni*16 + ln;
        bhf[ni] = *(const short8*)&Bh[cr*64 + s];
        blf[ni] = *(const short8*)&Bl[cr*64 + s];
      }
      #pragma unroll
      for (int mi = 0; mi < 4; ++mi) {
        int ar = wr*64 + mi*16 + ln;
        short8 ahf = *(const short8*)&Ah[ar*64 + s];
        short8 alf = *(const short8*)&Al[ar*64 + s];
        #pragma unroll
        for (int ni = 0; ni < 2; ++ni) {
          acc[mi][ni] = __builtin_amdgcn_mfma_f32_16x16x32_bf16(ahf, bhf[ni], acc[mi][ni], 0,0,0);
          acc[mi][ni] = __builtin_amdgcn_mfma_f32_16x16x32_bf16(ahf, blf[ni], acc[mi][ni], 0,0,0);
          acc[mi][ni] = __builtin_amdgcn_mfma_f32_16x16x32_bf16(alf, bhf[ni], acc[mi][ni], 0,0,0);
        }
      }
    }
  }
  __syncthreads();
  unsigned short* Trh = (unsigned short*)smem;     // [64 l][136]
  unsigned short* Trl = Trh + 64*136;
  #pragma unroll
  for (int mi = 0; mi < 4; ++mi)
    #pragma unroll
    for (int ni = 0; ni < 2; ++ni)
      #pragma unroll
      for (int j = 0; j < 4; ++j) {
        int rloc = wr*64 + mi*16 + g*4 + j;
        int cloc = wc*32 + ni*16 + ln;
        float bias = (rloc < 64) ? bq[rloc] : bk[rloc - 64];
        unsigned short hi, lo; split_bf16(acc[mi][ni][j] + bias, hi, lo);
        Trh[cloc*136 + rloc] = hi;
        Trl[cloc*136 + rloc] = lo;
      }
  __syncthreads();
  #pragma unroll
  for (int i = 0; i < 4; ++i) {
    int idx = tid + i*256;
    int l = idx >> 4, s = idx & 15;
    long row = ((long)b*LSEQ + nt*64 + l) * 64;
    short8 h  = *(const short8*)&Trh[l*136 + s*8];
    short8 lo = *(const short8*)&Trl[l*136 + s*8];
    if (s < 8) { *(short8*)&qh[row + s*8] = h;      *(short8*)&ql[row + s*8] = lo; }
    else       { *(short8*)&kh[row + (s-8)*8] = h;  *(short8*)&kl[row + (s-8)*8] = lo; }
  }
}

// ---------- Kernel 2: v projection (pure bf16 GEMM) -> bf16 [b][c][l] ----------
__global__ __launch_bounds__(256, 2) void v_proj(
    const unsigned short* __restrict__ xth,
    const unsigned short* __restrict__ Wvh,
    const float* __restrict__ bv,
    unsigned short* __restrict__ vws)
{
  const int lt = blockIdx.x;
  const int ct = blockIdx.y;
  const int b  = blockIdx.z;
  const int tid = threadIdx.x;
  const int wave = tid >> 6, lane = tid & 63;
  const int wr = wave >> 1, wc = wave & 1;
  const int g = lane >> 4, ln = lane & 15;

  __shared__ char smem[34816];
  unsigned short* Ahs = (unsigned short*)smem;
  unsigned short* Bhs = Ahs + 8192;

  const int rb = tid >> 3, jj = tid & 7;
  const int dst0 = rb*64 + ((jj ^ (rb & 7)) << 3);
  const long wbase = (long)(ct*128 + rb)*C_IN + jj*8;
  const long xbase = ((long)b*LSEQ + lt*128 + rb)*C_IN + jj*8;

  short8 rA[4], rB[4];
  #pragma unroll
  for (int j = 0; j < 4; ++j) {
    rA[j] = *(const short8*)&Wvh[wbase + (long)j*32*C_IN];
    rB[j] = *(const short8*)&xth[xbase + (long)j*32*C_IN];
  }

  f32x4 acc[4][4] = {};

  for (int kb = 0; kb < 8; ++kb) {
    __syncthreads();
    #pragma unroll
    for (int j = 0; j < 4; ++j) {
      *(short8*)&Ahs[dst0 + j*2048] = rA[j];
      *(short8*)&Bhs[dst0 + j*2048] = rB[j];
    }
    __syncthreads();
    if (kb < 7) {
      int ko = (kb+1)*64;
      #pragma unroll
      for (int j = 0; j < 4; ++j) {
        rA[j] = *(const short8*)&Wvh[wbase + (long)j*32*C_IN + ko];
        rB[j] = *(const short8*)&xth[xbase + (long)j*32*C_IN + ko];
      }
    }
    #pragma unroll
    for (int ks = 0; ks < 2; ++ks) {
      int s = ((ks*4 + g) ^ (ln & 7)) << 3;
      short8 bf[4];
      #pragma unroll
      for (int ni = 0; ni < 4; ++ni) {
        int cr = wc*64 + ni*16 + ln;
        bf[ni] = *(const short8*)&Bhs[cr*64 + s];
      }
      #pragma unroll
      for (int mi = 0; mi < 4; ++mi) {
        int ar = wr*64 + mi*16 + ln;
        short8 af = *(const short8*)&Ahs[ar*64 + s];
        #pragma unroll
        for (int ni = 0; ni < 4; ++ni)
          acc[mi][ni] = __builtin_amdgcn_mfma_f32_16x16x32_bf16(af, bf[ni], acc[mi][ni], 0,0,0);
      }
    }
  }
  __syncthreads();
  unsigned short* Tr = (unsigned short*)smem;
  #pragma unroll
  for (int mi = 0; mi < 4; ++mi)
    #pragma unroll
    for (int ni = 0; ni < 4; ++ni)
      #pragma unroll
      for (int j = 0; j < 4; ++j) {
        int rloc = wr*64 + mi*16 + g*4 + j;
        int cloc = wc*64 + ni*16 + ln;
        Tr[rloc*136 + cloc] = bf16_rn(acc[mi][ni][j] + bv[ct*128 + rloc]);
      }
  __syncthreads();
  #pragma unroll
  for (int i = 0; i < 8; ++i) {
    int idx = tid + i*256;
    int c = idx >> 4, s = idx & 15;
    *(short8*)&vws[((long)b*C_IN + ct*128 + c)*LSEQ + lt*128 + s*8] =
      *(const short8*)&Tr[c*136 + s*8];
  }
}

// ---------- Kernel 3 (FUSED): energy+softmax+attn-write+PV+out ----------
// grid 1024 linear (XCD-swizzled -> (lt, b)); 512 threads = 8 waves.
// LDS 128 KiB: Pb[32][1024] bf16 (swz) | union{ K[128][64] hi+lo , V[512][64] } | red
__global__ __launch_bounds__(512, 2) void fused_attn(
    const unsigned short* __restrict__ qh, const unsigned short* __restrict__ ql,
    const unsigned short* __restrict__ kh, const unsigned short* __restrict__ kl,
    const unsigned short* __restrict__ vws,
    const float* __restrict__ x, const float* __restrict__ gamma,
    float* __restrict__ attn, float* __restrict__ out)
{
  const int xg = blockIdx.x;
  const int b  = (xg & 7) | ((xg >> 8) << 3);   // all 32 lt of a b on one XCD
  const int lt = (xg >> 3) & 31;
  const int tid = threadIdx.x;
  const int w = tid >> 6, lane = tid & 63;
  const int g = lane >> 4, ln = lane & 15;

  __shared__ char smem[131072];
  unsigned short* Pb  = (unsigned short*)smem;            // [32][1024] swz, 64 KiB
  unsigned short* Kh  = (unsigned short*)(smem + 65536);  // [128][64]
  unsigned short* Kl  = Kh + 8192;
  unsigned short* Vst = (unsigned short*)(smem + 65536);  // [512][64] (aliases K)
  float* redM = (float*)(smem + 98304);                   // [8][32]
  float* redS = redM + 256;

  // ---- Q fragments (pre-split bf16, [b][l][64]) ----
  short8 ah[2][2], al[2][2];
  #pragma unroll
  for (int li = 0; li < 2; ++li)
    #pragma unroll
    for (int ks = 0; ks < 2; ++ks) {
      long qoff = ((long)b*LSEQ + lt*32 + li*16 + ln)*64 + ks*32 + g*8;
      ah[li][ks] = *(const short8*)&qh[qoff];
      al[li][ks] = *(const short8*)&ql[qoff];
    }

  // ---- QK^T: 8 chunks of 128 m ----
  const int r  = tid >> 3, jj = tid & 7;        // r 0..63
  const int kd0 = r*64 + ((jj ^ (r & 7)) << 3); // rows r, r+64 -> +64*64
  const long kb0 = ((long)b*LSEQ + r)*64 + jj*8;

  short8 pkh[2], pkl[2];
  #pragma unroll
  for (int j = 0; j < 2; ++j) {
    pkh[j] = *(const short8*)&kh[kb0 + j*4096];
    pkl[j] = *(const short8*)&kl[kb0 + j*4096];
  }

  f32x4 acc[8][2] = {};
  #pragma unroll
  for (int c = 0; c < 8; ++c) {
    __syncthreads();
    #pragma unroll
    for (int j = 0; j < 2; ++j) {
      *(short8*)&Kh[kd0 + j*4096] = pkh[j];
      *(short8*)&Kl[kd0 + j*4096] = pkl[j];
    }
    __syncthreads();
    if (c < 7) {
      #pragma unroll
      for (int j = 0; j < 2; ++j) {
        pkh[j] = *(const short8*)&kh[kb0 + (c+1)*8192 + j*4096];
        pkl[j] = *(const short8*)&kl[kb0 + (c+1)*8192 + j*4096];
      }
    }
    const int mloc = w*16 + ln;                 // this wave's m-16 of the chunk
    #pragma unroll
    for (int ks = 0; ks < 2; ++ks) {
      int s = ((ks*4 + g) ^ (mloc & 7)) << 3;
      short8 bh = *(const short8*)&Kh[mloc*64 + s];
      short8 bl = *(const short8*)&Kl[mloc*64 + s];
      #pragma unroll
      for (int li = 0; li < 2; ++li) {
        acc[c][li] = __builtin_amdgcn_mfma_f32_16x16x32_bf16(ah[li][ks], bh, acc[c][li], 0,0,0);
        acc[c][li] = __builtin_amdgcn_mfma_f32_16x16x32_bf16(ah[li][ks], bl, acc[c][li], 0,0,0);
        acc[c][li] = __builtin_amdgcn_mfma_f32_16x16x32_bf16(al[li][ks], bh, acc[c][li], 0,0,0);
      }
    }
  }

  // ---- softmax over m (rows l = li*16 + g*4 + j; cols spread ln x waves x c) ----
  float mx[2][4];
  #pragma unroll
  for (int li = 0; li < 2; ++li)
    #pragma unroll
    for (int j = 0; j < 4; ++j) {
      float m = acc[0][li][j];
      #pragma unroll
      for (int c = 1; c < 8; ++c) m = fmaxf(m, acc[c][li][j]);
      #pragma unroll
      for (int off = 1; off < 16; off <<= 1) m = fmaxf(m, __shfl_xor(m, off));
      mx[li][j] = m;
    }
  if (ln == 0) {
    #pragma unroll
    for (int li = 0; li < 2; ++li)
      #pragma unroll
      for (int j = 0; j < 4; ++j) redM[w*32 + li*16 + g*4 + j] = mx[li][j];
  }
  __syncthreads();
  #pragma unroll
  for (int li = 0; li < 2; ++li)
    #pragma unroll
    for (int j = 0; j < 4; ++j) {
      float m = redM[li*16 + g*4 + j];
      #pragma unroll
      for (int w2 = 1; w2 < 8; ++w2) m = fmaxf(m, redM[w2*32 + li*16 + g*4 + j]);
      mx[li][j] = m;
    }
  float inv[2][4];
  #pragma unroll
  for (int li = 0; li < 2; ++li)
    #pragma unroll
    for (int j = 0; j < 4; ++j) {
      float s = 0.f;
      #pragma unroll
      for (int c = 0; c < 8; ++c) {
        float p = __expf(acc[c][li][j] - mx[li][j]);
        acc[c][li][j] = p;
        s += p;
      }
      #pragma unroll
      for (int off = 1; off < 16; off <<= 1) s += __shfl_xor(s, off);
      inv[li][j] = s;
    }
  if (ln == 0) {
    #pragma unroll
    for (int li = 0; li < 2; ++li)
      #pragma unroll
      for (int j = 0; j < 4; ++j) redS[w*32 + li*16 + g*4 + j] = inv[li][j];
  }
  __syncthreads();
  #pragma unroll
  for (int li = 0; li < 2; ++li)
    #pragma unroll
    for (int j = 0; j < 4; ++j) {
      float s = redS[li*16 + g*4 + j];
      #pragma unroll
      for (int w2 = 1; w2 < 8; ++w2) s += redS[w2*32 + li*16 + g*4 + j];
      inv[li][j] = 1.0f / s;
    }

  // ---- P (bf16) -> Pb LDS [l][m], slot-swizzled ----
  #pragma unroll
  for (int c = 0; c < 8; ++c)
    #pragma unroll
    for (int li = 0; li < 2; ++li) {
      int m0 = c*128 + w*16 + ln;
      int slot = m0 >> 3, mlow = m0 & 7;
      #pragma unroll
      for (int j = 0; j < 4; ++j) {
        int l = li*16 + g*4 + j;
        Pb[l*1024 + ((slot ^ (l & 7)) << 3) + mlow] = bf16_rn(acc[c][li][j] * inv[li][j]);
      }
    }
  __syncthreads();

  // ---- V chunk 0 prefetch (V[512][64] per 64-m chunk) ----
  const int vd0 = kd0;                          // same [R][64] swizzle pattern
  const long vb0 = ((long)b*C_IN + r)*LSEQ + jj*8;
  short8 pv[8];
  #pragma unroll
  for (int j = 0; j < 8; ++j)
    pv[j] = *(const short8*)&vws[vb0 + (long)j*64*LSEQ];

  // ---- attention f32 write (from Pb, coalesced) ----
  {
    const int l = tid >> 4, seg = tid & 15;
    long arow = ((long)b*LSEQ + lt*32 + l)*LSEQ + seg*64;
    #pragma unroll
    for (int i = 0; i < 8; ++i) {
      int slot = seg*8 + i;
      short8 v = *(const short8*)&Pb[l*1024 + ((slot ^ (l & 7)) << 3)];
      f32x4 f0, f1;
      #pragma unroll
      for (int q = 0; q < 4; ++q) {
        f0[q] = bf16_to_f32((unsigned short)v[q]);
        f1[q] = bf16_to_f32((unsigned short)v[q+4]);
      }
      *(f32x4*)&attn[arow + i*8]     = f0;
      *(f32x4*)&attn[arow + i*8 + 4] = f1;
    }
  }

  // ---- PV: 16 chunks of 64 m; out tile [512 c][32 l], wave w owns 64 c ----
  f32x4 acc2[4][2] = {};
  for (int mb = 0; mb < 16; ++mb) {
    __syncthreads();
    #pragma unroll
    for (int j = 0; j < 8; ++j)
      *(short8*)&Vst[vd0 + j*4096] = pv[j];
    __syncthreads();
    if (mb < 15) {
      #pragma unroll
      for (int j = 0; j < 8; ++j)
        pv[j] = *(const short8*)&vws[vb0 + (long)j*64*LSEQ + (mb+1)*64];
    }
    #pragma unroll
    for (int kv = 0; kv < 2; ++kv) {
      short8 bf[2];
      #pragma unroll
      for (int lf = 0; lf < 2; ++lf) {
        int l = lf*16 + ln;
        int slot = mb*8 + kv*4 + g;
        bf[lf] = *(const short8*)&Pb[l*1024 + ((slot ^ (l & 7)) << 3)];
      }
      #pragma unroll
      for (int cf = 0; cf < 4; ++cf) {
        int cr = w*64 + cf*16 + ln;
        short8 af = *(const short8*)&Vst[cr*64 + (((kv*4 + g) ^ (cr & 7)) << 3)];
        #pragma unroll
        for (int lf = 0; lf < 2; ++lf)
          acc2[cf][lf] = __builtin_amdgcn_mfma_f32_16x16x32_bf16(af, bf[lf], acc2[cf][lf], 0,0,0);
      }
    }
  }

  // ---- epilogue: out = gamma * PV + x ----
  const float gm = gamma[0];
  #pragma unroll
  for (int cf = 0; cf < 4; ++cf)
    #pragma unroll
    for (int lf = 0; lf < 2; ++lf)
      #pragma unroll
      for (int j = 0; j < 4; ++j) {
        int c = w*64 + cf*16 + g*4 + j;
        int l = lt*32 + lf*16 + ln;
        long o = ((long)b*C_IN + c)*LSEQ + l;
        out[o] = gm * acc2[cf][lf][j] + x[o];
      }
}

extern "C" void kernel_launch(void* const* d_in, const int* in_sizes, int n_in,
                              void* d_out, int out_size, void* d_ws, size_t ws_size,
                              hipStream_t stream)
{
  const float* x  = (const float*)d_in[0];
  const float* Wq = (const float*)d_in[1];
  const float* bq = (const float*)d_in[2];
  const float* Wk = (const float*)d_in[3];
  const float* bk = (const float*)d_in[4];
  const float* Wv = (const float*)d_in[5];
  const float* bv = (const float*)d_in[6];
  const float* gamma = (const float*)d_in[7];
  float* out  = (float*)d_out;
  float* attn = out + OUT_ELEMS;

  char* ws = (char*)d_ws;
  unsigned short* Wqh = (unsigned short*)(ws + 0);
  unsigned short* Wql = (unsigned short*)(ws + 65536);
  unsigned short* Wkh = (unsigned short*)(ws + 131072);
  unsigned short* Wkl = (unsigned short*)(ws + 196608);
  unsigned short* Wvh = (unsigned short*)(ws + 262144);
  unsigned short* qhp = (unsigned short*)(ws + 786432);
  unsigned short* qlp = (unsigned short*)(ws + 786432 + 1ul*4194304);
  unsigned short* khp = (unsigned short*)(ws + 786432 + 2ul*4194304);
  unsigned short* klp = (unsigned short*)(ws + 786432 + 3ul*4194304);
  unsigned short* vws = (unsigned short*)(ws + 786432 + 4ul*4194304);
  char* uni = ws + 786432 + 4ul*4194304 + 33554432;
  unsigned short* xth  = (unsigned short*)uni;                    // 32 MiB
  unsigned short* xtl  = (unsigned short*)(uni + 33554432);       // 32 MiB

  split_weights<<<320, 256, 0, stream>>>(Wq, Wk, Wv, Wqh, Wql, Wkh, Wkl, Wvh);
  transpose_split<<<dim3(16, 8, B_SZ), 256, 0, stream>>>(x, xth, xtl);
  qk_proj<<<dim3(16, B_SZ), 256, 0, stream>>>(xth, xtl, Wqh, Wql, Wkh, Wkl, bq, bk, qhp, qlp, khp, klp);
  v_proj<<<dim3(8, 4, B_SZ), 256, 0, stream>>>(xth, Wvh, bv, vws);
  fused_attn<<<1024, 512, 0, stream>>>(qhp, qlp, khp, klp, vws, x, gamma, attn, out);
}

// Round 8
// 202.729 us; speedup vs baseline: 1.2566x; 1.2566x over previous
//
#include <hip/hip_runtime.h>

typedef __attribute__((ext_vector_type(8))) short short8;
typedef __attribute__((ext_vector_type(4))) float f32x4;

#define B_SZ 32
#define C_IN 512
#define C8V 64
#define LSEQ 1024
#define OUT_ELEMS (B_SZ * C_IN * LSEQ)

__device__ inline unsigned short bf16_rn(float f) {
  unsigned int u = __float_as_uint(f);
  unsigned int r = 0x7FFFu + ((u >> 16) & 1u);
  return (unsigned short)((u + r) >> 16);
}
__device__ inline float bf16_to_f32(unsigned short h) {
  return __uint_as_float(((unsigned int)h) << 16);
}
__device__ inline void split_bf16(float f, unsigned short &hi, unsigned short &lo) {
  hi = bf16_rn(f);
  lo = bf16_rn(f - bf16_to_f32(hi));
}

// ---------- Kernel 0: pre-split weights into bf16 hi/lo planes ----------
__global__ __launch_bounds__(256) void split_weights(
    const float* __restrict__ Wq, const float* __restrict__ Wk, const float* __restrict__ Wv,
    unsigned short* __restrict__ Wqh, unsigned short* __restrict__ Wql,
    unsigned short* __restrict__ Wkh, unsigned short* __restrict__ Wkl,
    unsigned short* __restrict__ Wvh)
{
  int i = (blockIdx.x * 256 + threadIdx.x) * 4;
  if (i < 262144) {
    f32x4 f = *(const f32x4*)&Wv[i];
    #pragma unroll
    for (int j = 0; j < 4; ++j) Wvh[i + j] = bf16_rn(f[j]);
  } else if (i < 294912) {
    int k = i - 262144;
    f32x4 f = *(const f32x4*)&Wq[k];
    #pragma unroll
    for (int j = 0; j < 4; ++j) { unsigned short h, l; split_bf16(f[j], h, l); Wqh[k+j] = h; Wql[k+j] = l; }
  } else {
    int k = i - 294912;
    f32x4 f = *(const f32x4*)&Wk[k];
    #pragma unroll
    for (int j = 0; j < 4; ++j) { unsigned short h, l; split_bf16(f[j], h, l); Wkh[k+j] = h; Wkl[k+j] = l; }
  }
}

// ---------- Kernel 1: q,k projection -> pre-split [b][l][64] hi/lo planes ----------
__global__ __launch_bounds__(256, 2) void qk_proj(
    const float* __restrict__ x,
    const unsigned short* __restrict__ Wqh, const unsigned short* __restrict__ Wql,
    const unsigned short* __restrict__ Wkh, const unsigned short* __restrict__ Wkl,
    const float* __restrict__ bq, const float* __restrict__ bk,
    unsigned short* __restrict__ qh, unsigned short* __restrict__ ql,
    unsigned short* __restrict__ kh, unsigned short* __restrict__ kl)
{
  const int nt = blockIdx.x;
  const int b  = blockIdx.y;
  const int tid = threadIdx.x;
  const int wave = tid >> 6, lane = tid & 63;
  const int wr = wave >> 1, wc = wave & 1;
  const int g = lane >> 4, ln = lane & 15;

  __shared__ char smem[66560];
  unsigned short* Ah = (unsigned short*)smem;
  unsigned short* Al = Ah + 128*64;
  unsigned short* Bh = Al + 128*64;
  unsigned short* Bl = Bh + 64*64;
  float* xs = (float*)(Bl + 64*64);

  f32x4 acc[4][2] = {};

  for (int kb = 0; kb < 8; ++kb) {
    if (kb) __syncthreads();
    #pragma unroll
    for (int i = 0; i < 4; ++i) {
      int idx = tid + i*256;
      int r = idx >> 3, jj = idx & 7;
      const unsigned short* sH = (r < 64) ? &Wqh[r*512 + kb*64 + jj*8]
                                          : &Wkh[(r-64)*512 + kb*64 + jj*8];
      const unsigned short* sL = (r < 64) ? &Wql[r*512 + kb*64 + jj*8]
                                          : &Wkl[(r-64)*512 + kb*64 + jj*8];
      int dst = r*64 + ((jj ^ (r & 7)) << 3);
      *(short8*)&Ah[dst] = *(const short8*)sH;
      *(short8*)&Al[dst] = *(const short8*)sL;
    }
    #pragma unroll
    for (int i = 0; i < 4; ++i) {
      int idx = tid + i*256;
      int kk = idx >> 4, l4 = idx & 15;
      f32x4 v = *(const f32x4*)&x[((long)b*C_IN + kb*64 + kk)*LSEQ + nt*64 + l4*4];
      *(f32x4*)&xs[kk*68 + l4*4] = v;
    }
    __syncthreads();
    {
      int l = tid & 63, kc = (tid >> 6) * 16;
      unsigned short hbuf[16], lbuf[16];
      #pragma unroll
      for (int i = 0; i < 16; ++i) split_bf16(xs[(kc + i)*68 + l], hbuf[i], lbuf[i]);
      #pragma unroll
      for (int s2 = 0; s2 < 2; ++s2) {
        int s = (kc >> 3) + s2;
        int dst = l*64 + ((s ^ (l & 7)) << 3);
        *(short8*)&Bh[dst] = *(const short8*)&hbuf[s2*8];
        *(short8*)&Bl[dst] = *(const short8*)&lbuf[s2*8];
      }
    }
    __syncthreads();
    #pragma unroll
    for (int ks = 0; ks < 2; ++ks) {
      short8 bhf[2], blf[2];
      #pragma unroll
      for (int ni = 0; ni < 2; ++ni) {
        int cr = wc*32 + ni*16 + ln;
        int s = ((ks*4 + g) ^ (cr & 7)) << 3;
        bhf[ni] = *(const short8*)&Bh[cr*64 + s];
        blf[ni] = *(const short8*)&Bl[cr*64 + s];
      }
      #pragma unroll
      for (int mi = 0; mi < 4; ++mi) {
        int ar = wr*64 + mi*16 + ln;
        int s = ((ks*4 + g) ^ (ar & 7)) << 3;
        short8 ahf = *(const short8*)&Ah[ar*64 + s];
        short8 alf = *(const short8*)&Al[ar*64 + s];
        #pragma unroll
        for (int ni = 0; ni < 2; ++ni) {
          acc[mi][ni] = __builtin_amdgcn_mfma_f32_16x16x32_bf16(ahf, bhf[ni], acc[mi][ni], 0,0,0);
          acc[mi][ni] = __builtin_amdgcn_mfma_f32_16x16x32_bf16(ahf, blf[ni], acc[mi][ni], 0,0,0);
          acc[mi][ni] = __builtin_amdgcn_mfma_f32_16x16x32_bf16(alf, bhf[ni], acc[mi][ni], 0,0,0);
        }
      }
    }
  }
  __syncthreads();
  unsigned short* Trh = (unsigned short*)smem;
  unsigned short* Trl = Trh + 64*136;
  #pragma unroll
  for (int mi = 0; mi < 4; ++mi)
    #pragma unroll
    for (int ni = 0; ni < 2; ++ni)
      #pragma unroll
      for (int j = 0; j < 4; ++j) {
        int rloc = wr*64 + mi*16 + g*4 + j;
        int cloc = wc*32 + ni*16 + ln;
        float bias = (rloc < 64) ? bq[rloc] : bk[rloc - 64];
        unsigned short hi, lo; split_bf16(acc[mi][ni][j] + bias, hi, lo);
        Trh[cloc*136 + rloc] = hi;
        Trl[cloc*136 + rloc] = lo;
      }
  __syncthreads();
  #pragma unroll
  for (int i = 0; i < 4; ++i) {
    int idx = tid + i*256;
    int l = idx >> 4, s = idx & 15;
    long row = ((long)b*LSEQ + nt*64 + l) * 64;
    short8 h  = *(const short8*)&Trh[l*136 + s*8];
    short8 lo = *(const short8*)&Trl[l*136 + s*8];
    if (s < 8) { *(short8*)&qh[row + s*8] = h;      *(short8*)&ql[row + s*8] = lo; }
    else       { *(short8*)&kh[row + (s-8)*8] = h;  *(short8*)&kl[row + (s-8)*8] = lo; }
  }
}

// ---------- Kernel 2: v projection -> bf16 [b][c][l] ----------
__global__ __launch_bounds__(256, 2) void v_proj(
    const float* __restrict__ x,
    const unsigned short* __restrict__ Wvh,
    const float* __restrict__ bv,
    unsigned short* __restrict__ vws)
{
  const int lt = blockIdx.x;
  const int ct = blockIdx.y;
  const int b  = blockIdx.z;
  const int tid = threadIdx.x;
  const int wave = tid >> 6, lane = tid & 63;
  const int wr = wave >> 1, wc = wave & 1;
  const int g = lane >> 4, ln = lane & 15;

  __shared__ char smem[66560];
  unsigned short* Ahs = (unsigned short*)smem;
  unsigned short* Bhs = Ahs + 8192;
  float* xs = (float*)(Bhs + 8192);

  f32x4 acc[4][4] = {};

  for (int kb = 0; kb < 8; ++kb) {
    if (kb) __syncthreads();
    #pragma unroll
    for (int i = 0; i < 4; ++i) {
      int idx = tid + i*256;
      int r = idx >> 3, jj = idx & 7;
      *(short8*)&Ahs[r*64 + ((jj ^ (r & 7)) << 3)] =
        *(const short8*)&Wvh[(ct*128 + r)*512 + kb*64 + jj*8];
    }
    #pragma unroll
    for (int i = 0; i < 8; ++i) {
      int idx = tid + i*256;
      int kk = idx >> 5, l4 = idx & 31;
      f32x4 v = *(const f32x4*)&x[((long)b*C_IN + kb*64 + kk)*LSEQ + lt*128 + l4*4];
      *(f32x4*)&xs[kk*132 + l4*4] = v;
    }
    __syncthreads();
    {
      int l = tid & 127, kc = (tid >> 7) * 32;
      unsigned short hbuf[32];
      #pragma unroll
      for (int i = 0; i < 32; ++i) hbuf[i] = bf16_rn(xs[(kc + i)*132 + l]);
      #pragma unroll
      for (int s2 = 0; s2 < 4; ++s2) {
        int s = (kc >> 3) + s2;
        *(short8*)&Bhs[l*64 + ((s ^ (l & 7)) << 3)] = *(const short8*)&hbuf[s2*8];
      }
    }
    __syncthreads();
    #pragma unroll
    for (int ks = 0; ks < 2; ++ks) {
      short8 bf[4];
      #pragma unroll
      for (int ni = 0; ni < 4; ++ni) {
        int cr = wc*64 + ni*16 + ln;
        bf[ni] = *(const short8*)&Bhs[cr*64 + (((ks*4 + g) ^ (cr & 7)) << 3)];
      }
      #pragma unroll
      for (int mi = 0; mi < 4; ++mi) {
        int ar = wr*64 + mi*16 + ln;
        short8 af = *(const short8*)&Ahs[ar*64 + (((ks*4 + g) ^ (ar & 7)) << 3)];
        #pragma unroll
        for (int ni = 0; ni < 4; ++ni)
          acc[mi][ni] = __builtin_amdgcn_mfma_f32_16x16x32_bf16(af, bf[ni], acc[mi][ni], 0,0,0);
      }
    }
  }
  __syncthreads();
  unsigned short* Tr = (unsigned short*)smem;
  #pragma unroll
  for (int mi = 0; mi < 4; ++mi)
    #pragma unroll
    for (int ni = 0; ni < 4; ++ni)
      #pragma unroll
      for (int j = 0; j < 4; ++j) {
        int rloc = wr*64 + mi*16 + g*4 + j;
        int cloc = wc*64 + ni*16 + ln;
        Tr[rloc*136 + cloc] = bf16_rn(acc[mi][ni][j] + bv[ct*128 + rloc]);
      }
  __syncthreads();
  #pragma unroll
  for (int i = 0; i < 8; ++i) {
    int idx = tid + i*256;
    int c = idx >> 4, s = idx & 15;
    *(short8*)&vws[((long)b*C_IN + ct*128 + c)*LSEQ + lt*128 + s*8] =
      *(const short8*)&Tr[c*136 + s*8];
  }
}

// ---------- Kernel 3: energy + softmax -> attn f32 (d_out) + P bf16 copy ----------
// linear grid 2048, XCD-swizzled: all 64 l-tiles of batch b on XCD b%8.
__global__ __launch_bounds__(256, 2) void energy_softmax(
    const unsigned short* __restrict__ qh, const unsigned short* __restrict__ ql,
    const unsigned short* __restrict__ kh, const unsigned short* __restrict__ kl,
    float* __restrict__ attn, unsigned short* __restrict__ pbuf)
{
  const int gi = blockIdx.x;
  const int b  = (gi & 7) + 8 * (gi >> 9);
  const int lt = (gi >> 3) & 63;
  const int tid = threadIdx.x;
  const int wave = tid >> 6, lane = tid & 63;
  const int g = lane >> 4, ln = lane & 15;

  __shared__ unsigned short Ksm[16640];
  __shared__ float redM[4][16];
  __shared__ float redS[4][16];
  unsigned short* Kh = Ksm;
  unsigned short* Kl = Ksm + 8192;

  short8 ah[2], al[2];
  {
    long qrow = ((long)b*LSEQ + lt*16 + ln) * 64;
    #pragma unroll
    for (int ks = 0; ks < 2; ++ks) {
      ah[ks] = *(const short8*)&qh[qrow + ks*32 + g*8];
      al[ks] = *(const short8*)&ql[qrow + ks*32 + g*8];
    }
  }

  const int rb = tid >> 3, jj = tid & 7;
  const int dst0 = rb*64 + ((jj ^ (rb & 7)) << 3);
  const long kbase = ((long)b*LSEQ + rb)*64 + jj*8;

  short8 rkh[4], rkl[4];
  #pragma unroll
  for (int j = 0; j < 4; ++j) {
    rkh[j] = *(const short8*)&kh[kbase + j*2048];
    rkl[j] = *(const short8*)&kl[kbase + j*2048];
  }

  f32x4 acc[8][2] = {};
  #pragma unroll
  for (int c = 0; c < 8; ++c) {
    __syncthreads();
    #pragma unroll
    for (int j = 0; j < 4; ++j) {
      *(short8*)&Kh[dst0 + j*2048] = rkh[j];
      *(short8*)&Kl[dst0 + j*2048] = rkl[j];
    }
    __syncthreads();
    if (c < 7) {
      #pragma unroll
      for (int j = 0; j < 4; ++j) {
        rkh[j] = *(const short8*)&kh[kbase + (long)(c+1)*8192 + j*2048];
        rkl[j] = *(const short8*)&kl[kbase + (long)(c+1)*8192 + j*2048];
      }
    }
    #pragma unroll
    for (int fq = 0; fq < 2; ++fq) {
      int mloc = wave*32 + fq*16 + ln;
      #pragma unroll
      for (int ks = 0; ks < 2; ++ks) {
        int s = ((ks*4 + g) ^ (mloc & 7)) << 3;
        short8 bh = *(const short8*)&Kh[mloc*64 + s];
        short8 bl = *(const short8*)&Kl[mloc*64 + s];
        acc[c][fq] = __builtin_amdgcn_mfma_f32_16x16x32_bf16(ah[ks], bh, acc[c][fq], 0,0,0);
        acc[c][fq] = __builtin_amdgcn_mfma_f32_16x16x32_bf16(ah[ks], bl, acc[c][fq], 0,0,0);
        acc[c][fq] = __builtin_amdgcn_mfma_f32_16x16x32_bf16(al[ks], bh, acc[c][fq], 0,0,0);
      }
    }
  }

  float mx[4];
  #pragma unroll
  for (int j = 0; j < 4; ++j) {
    float m = -1e30f;
    #pragma unroll
    for (int c = 0; c < 8; ++c)
      #pragma unroll
      for (int fq = 0; fq < 2; ++fq) m = fmaxf(m, acc[c][fq][j]);
    #pragma unroll
    for (int off = 1; off < 16; off <<= 1) m = fmaxf(m, __shfl_xor(m, off));
    mx[j] = m;
  }
  if (ln == 0) {
    #pragma unroll
    for (int j = 0; j < 4; ++j) redM[wave][g*4+j] = mx[j];
  }
  __syncthreads();
  #pragma unroll
  for (int j = 0; j < 4; ++j) {
    float m = redM[0][g*4+j];
    #pragma unroll
    for (int w = 1; w < 4; ++w) m = fmaxf(m, redM[w][g*4+j]);
    mx[j] = m;
  }
  float sm[4];
  #pragma unroll
  for (int j = 0; j < 4; ++j) {
    float s = 0.f;
    #pragma unroll
    for (int c = 0; c < 8; ++c)
      #pragma unroll
      for (int fq = 0; fq < 2; ++fq) {
        float p = expf(acc[c][fq][j] - mx[j]);
        acc[c][fq][j] = p;
        s += p;
      }
    #pragma unroll
    for (int off = 1; off < 16; off <<= 1) s += __shfl_xor(s, off);
    sm[j] = s;
  }
  if (ln == 0) {
    #pragma unroll
    for (int j = 0; j < 4; ++j) redS[wave][g*4+j] = sm[j];
  }
  __syncthreads();
  #pragma unroll
  for (int j = 0; j < 4; ++j) {
    float s = redS[0][g*4+j];
    #pragma unroll
    for (int w = 1; w < 4; ++w) s += redS[w][g*4+j];
    sm[j] = 1.0f / s;
  }

  unsigned short* Pb = Ksm;              // [16][1032]
  __syncthreads();
  #pragma unroll
  for (int c = 0; c < 8; ++c)
    #pragma unroll
    for (int fq = 0; fq < 2; ++fq) {
      int m0 = c*128 + wave*32 + fq*16 + ln;
      #pragma unroll
      for (int j = 0; j < 4; ++j)
        Pb[(g*4+j)*1032 + m0] = bf16_rn(acc[c][fq][j] * sm[j]);
    }
  __syncthreads();
  #pragma unroll
  for (int u = 0; u < 8; ++u) {
    int cid = tid + u*256;
    int row = cid >> 7, col = (cid & 127) * 8;
    short8 v = *(const short8*)&Pb[row*1032 + col];
    long gro = ((long)b*LSEQ + lt*16 + row)*LSEQ + col;
    *(short8*)&pbuf[gro] = v;
    f32x4 f0, f1;
    #pragma unroll
    for (int i = 0; i < 4; ++i) {
      f0[i] = bf16_to_f32((unsigned short)v[i]);
      f1[i] = bf16_to_f32((unsigned short)v[i+4]);
    }
    *(f32x4*)&attn[gro] = f0;
    *(f32x4*)&attn[gro + 4] = f1;
  }
}

// ---------- Kernel 4: out = gamma * (V @ P^T) + x ----------
// 512 threads, 8 waves; tile 128c x 256l; linear grid 512, XCD-swizzled.
__global__ __launch_bounds__(512, 2) void pv_out(
    const unsigned short* __restrict__ vws,
    const unsigned short* __restrict__ pbuf,
    const float* __restrict__ x,
    const float* __restrict__ gamma,
    float* __restrict__ out)
{
  const int gi = blockIdx.x;             // 512 blocks: 16 per b, b -> XCD b%8
  const int b  = (gi & 7) + 8 * (gi >> 7);
  const int t  = (gi >> 3) & 15;
  const int lt = t >> 2, ct = t & 3;     // lt: 4 tiles of 256 l; ct: 4 tiles of 128 c
  const int tid = threadIdx.x;
  const int w = tid >> 6, lane = tid & 63;
  const int wcq = w >> 2, wlq = w & 3;   // wave -> (64c, 64l) sub-tile
  const int g = lane >> 4, ln = lane & 15;

  __shared__ char smem[49152];
  unsigned short* Vst = (unsigned short*)smem;            // [128][64] swz 16KB
  unsigned short* Pst = (unsigned short*)(smem + 16384);  // [256][64] swz 32KB

  // V staging: 512 thr -> rows 128 x 2 slots
  const int vr = tid >> 2, vs0 = (tid & 3) * 2;
  const long vbase = ((long)b*C_IN + ct*128 + vr)*LSEQ + vs0*8;
  // P staging: 512 thr -> rows 256 x 4 slots
  const int pr = tid >> 1, ps0 = (tid & 1) * 4;
  const long pbase = ((long)b*LSEQ + lt*256 + pr)*LSEQ + ps0*8;

  f32x4 acc[4][4] = {};
  short8 rv[2], rp[4];
  #pragma unroll
  for (int j = 0; j < 2; ++j) rv[j] = *(const short8*)&vws[vbase + j*8];
  #pragma unroll
  for (int j = 0; j < 4; ++j) rp[j] = *(const short8*)&pbuf[pbase + j*8];

  for (int mb = 0; mb < 16; ++mb) {
    __syncthreads();
    #pragma unroll
    for (int j = 0; j < 2; ++j)
      *(short8*)&Vst[vr*64 + (((vs0 + j) ^ (vr & 7)) << 3)] = rv[j];
    #pragma unroll
    for (int j = 0; j < 4; ++j)
      *(short8*)&Pst[pr*64 + (((ps0 + j) ^ (pr & 7)) << 3)] = rp[j];
    __syncthreads();
    if (mb < 15) {
      #pragma unroll
      for (int j = 0; j < 2; ++j) rv[j] = *(const short8*)&vws[vbase + (mb+1)*64 + j*8];
      #pragma unroll
      for (int j = 0; j < 4; ++j) rp[j] = *(const short8*)&pbuf[pbase + (mb+1)*64 + j*8];
    }
    #pragma unroll
    for (int ks = 0; ks < 2; ++ks) {
      short8 bf[4];
      #pragma unroll
      for (int lf = 0; lf < 4; ++lf) {
        int prow = wlq*64 + lf*16 + ln;
        bf[lf] = *(const short8*)&Pst[prow*64 + (((ks*4 + g) ^ (prow & 7)) << 3)];
      }
      #pragma unroll
      for (int cf = 0; cf < 4; ++cf) {
        int cr = wcq*64 + cf*16 + ln;
        short8 af = *(const short8*)&Vst[cr*64 + (((ks*4 + g) ^ (cr & 7)) << 3)];
        #pragma unroll
        for (int lf = 0; lf < 4; ++lf)
          acc[cf][lf] = __builtin_amdgcn_mfma_f32_16x16x32_bf16(af, bf[lf], acc[cf][lf], 0,0,0);
      }
    }
  }

  const float gm = gamma[0];
  #pragma unroll
  for (int cf = 0; cf < 4; ++cf)
    #pragma unroll
    for (int lf = 0; lf < 4; ++lf)
      #pragma unroll
      for (int j = 0; j < 4; ++j) {
        int c = ct*128 + wcq*64 + cf*16 + g*4 + j;
        int l = lt*256 + wlq*64 + lf*16 + ln;
        long o = ((long)b*C_IN + c)*LSEQ + l;
        out[o] = gm * acc[cf][lf][j] + x[o];
      }
}

extern "C" void kernel_launch(void* const* d_in, const int* in_sizes, int n_in,
                              void* d_out, int out_size, void* d_ws, size_t ws_size,
                              hipStream_t stream)
{
  const float* x  = (const float*)d_in[0];
  const float* Wq = (const float*)d_in[1];
  const float* bq = (const float*)d_in[2];
  const float* Wk = (const float*)d_in[3];
  const float* bk = (const float*)d_in[4];
  const float* Wv = (const float*)d_in[5];
  const float* bv = (const float*)d_in[6];
  const float* gamma = (const float*)d_in[7];
  float* out  = (float*)d_out;
  float* attn = out + OUT_ELEMS;

  char* ws = (char*)d_ws;
  unsigned short* Wqh = (unsigned short*)(ws + 0);
  unsigned short* Wql = (unsigned short*)(ws + 65536);
  unsigned short* Wkh = (unsigned short*)(ws + 131072);
  unsigned short* Wkl = (unsigned short*)(ws + 196608);
  unsigned short* Wvh = (unsigned short*)(ws + 262144);
  unsigned short* qhp = (unsigned short*)(ws + 786432);
  unsigned short* qlp = (unsigned short*)(ws + 786432 + 1ul*4194304);
  unsigned short* khp = (unsigned short*)(ws + 786432 + 2ul*4194304);
  unsigned short* klp = (unsigned short*)(ws + 786432 + 3ul*4194304);
  unsigned short* vws = (unsigned short*)(ws + 786432 + 4ul*4194304);
  unsigned short* pbuf = (unsigned short*)(ws + 786432 + 4ul*4194304 + 33554432);

  split_weights<<<320, 256, 0, stream>>>(Wq, Wk, Wv, Wqh, Wql, Wkh, Wkl, Wvh);
  qk_proj<<<dim3(16, B_SZ), 256, 0, stream>>>(x, Wqh, Wql, Wkh, Wkl, bq, bk, qhp, qlp, khp, klp);
  v_proj<<<dim3(8, 4, B_SZ), 256, 0, stream>>>(x, Wvh, bv, vws);
  energy_softmax<<<2048, 256, 0, stream>>>(qhp, qlp, khp, klp, attn, pbuf);
  pv_out<<<512, 512, 0, stream>>>(vws, pbuf, x, gamma, out);
}

// Round 9
// 190.525 us; speedup vs baseline: 1.3371x; 1.0641x over previous
//
#include <hip/hip_runtime.h>

typedef __attribute__((ext_vector_type(8))) short short8;
typedef __attribute__((ext_vector_type(4))) float f32x4;

#define B_SZ 32
#define C_IN 512
#define C8V 64
#define LSEQ 1024
#define OUT_ELEMS (B_SZ * C_IN * LSEQ)

__device__ inline unsigned short bf16_rn(float f) {
  unsigned int u = __float_as_uint(f);
  unsigned int r = 0x7FFFu + ((u >> 16) & 1u);
  return (unsigned short)((u + r) >> 16);
}
__device__ inline float bf16_to_f32(unsigned short h) {
  return __uint_as_float(((unsigned int)h) << 16);
}
__device__ inline void split_bf16(float f, unsigned short &hi, unsigned short &lo) {
  hi = bf16_rn(f);
  lo = bf16_rn(f - bf16_to_f32(hi));
}

// ---------- Kernel 0: pre-split weights into bf16 hi/lo planes ----------
__global__ __launch_bounds__(256) void split_weights(
    const float* __restrict__ Wq, const float* __restrict__ Wk, const float* __restrict__ Wv,
    unsigned short* __restrict__ Wqh, unsigned short* __restrict__ Wql,
    unsigned short* __restrict__ Wkh, unsigned short* __restrict__ Wkl,
    unsigned short* __restrict__ Wvh)
{
  int i = (blockIdx.x * 256 + threadIdx.x) * 4;
  if (i < 262144) {
    f32x4 f = *(const f32x4*)&Wv[i];
    #pragma unroll
    for (int j = 0; j < 4; ++j) Wvh[i + j] = bf16_rn(f[j]);
  } else if (i < 294912) {
    int k = i - 262144;
    f32x4 f = *(const f32x4*)&Wq[k];
    #pragma unroll
    for (int j = 0; j < 4; ++j) { unsigned short h, l; split_bf16(f[j], h, l); Wqh[k+j] = h; Wql[k+j] = l; }
  } else {
    int k = i - 294912;
    f32x4 f = *(const f32x4*)&Wk[k];
    #pragma unroll
    for (int j = 0; j < 4; ++j) { unsigned short h, l; split_bf16(f[j], h, l); Wkh[k+j] = h; Wkl[k+j] = l; }
  }
}

// ---------- Kernel 1: q,k projection -> pre-split [b][l][64] hi/lo planes ----------
__global__ __launch_bounds__(256, 2) void qk_proj(
    const float* __restrict__ x,
    const unsigned short* __restrict__ Wqh, const unsigned short* __restrict__ Wql,
    const unsigned short* __restrict__ Wkh, const unsigned short* __restrict__ Wkl,
    const float* __restrict__ bq, const float* __restrict__ bk,
    unsigned short* __restrict__ qh, unsigned short* __restrict__ ql,
    unsigned short* __restrict__ kh, unsigned short* __restrict__ kl)
{
  const int nt = blockIdx.x;
  const int b  = blockIdx.y;
  const int tid = threadIdx.x;
  const int wave = tid >> 6, lane = tid & 63;
  const int wr = wave >> 1, wc = wave & 1;
  const int g = lane >> 4, ln = lane & 15;

  __shared__ char smem[66560];
  unsigned short* Ah = (unsigned short*)smem;
  unsigned short* Al = Ah + 128*64;
  unsigned short* Bh = Al + 128*64;
  unsigned short* Bl = Bh + 64*64;
  float* xs = (float*)(Bl + 64*64);

  f32x4 acc[4][2] = {};

  for (int kb = 0; kb < 8; ++kb) {
    if (kb) __syncthreads();
    #pragma unroll
    for (int i = 0; i < 4; ++i) {
      int idx = tid + i*256;
      int r = idx >> 3, jj = idx & 7;
      const unsigned short* sH = (r < 64) ? &Wqh[r*512 + kb*64 + jj*8]
                                          : &Wkh[(r-64)*512 + kb*64 + jj*8];
      const unsigned short* sL = (r < 64) ? &Wql[r*512 + kb*64 + jj*8]
                                          : &Wkl[(r-64)*512 + kb*64 + jj*8];
      int dst = r*64 + ((jj ^ (r & 7)) << 3);
      *(short8*)&Ah[dst] = *(const short8*)sH;
      *(short8*)&Al[dst] = *(const short8*)sL;
    }
    #pragma unroll
    for (int i = 0; i < 4; ++i) {
      int idx = tid + i*256;
      int kk = idx >> 4, l4 = idx & 15;
      f32x4 v = *(const f32x4*)&x[((long)b*C_IN + kb*64 + kk)*LSEQ + nt*64 + l4*4];
      *(f32x4*)&xs[kk*68 + l4*4] = v;
    }
    __syncthreads();
    {
      int l = tid & 63, kc = (tid >> 6) * 16;
      unsigned short hbuf[16], lbuf[16];
      #pragma unroll
      for (int i = 0; i < 16; ++i) split_bf16(xs[(kc + i)*68 + l], hbuf[i], lbuf[i]);
      #pragma unroll
      for (int s2 = 0; s2 < 2; ++s2) {
        int s = (kc >> 3) + s2;
        int dst = l*64 + ((s ^ (l & 7)) << 3);
        *(short8*)&Bh[dst] = *(const short8*)&hbuf[s2*8];
        *(short8*)&Bl[dst] = *(const short8*)&lbuf[s2*8];
      }
    }
    __syncthreads();
    __builtin_amdgcn_s_setprio(1);
    #pragma unroll
    for (int ks = 0; ks < 2; ++ks) {
      short8 bhf[2], blf[2];
      #pragma unroll
      for (int ni = 0; ni < 2; ++ni) {
        int cr = wc*32 + ni*16 + ln;
        int s = ((ks*4 + g) ^ (cr & 7)) << 3;
        bhf[ni] = *(const short8*)&Bh[cr*64 + s];
        blf[ni] = *(const short8*)&Bl[cr*64 + s];
      }
      #pragma unroll
      for (int mi = 0; mi < 4; ++mi) {
        int ar = wr*64 + mi*16 + ln;
        int s = ((ks*4 + g) ^ (ar & 7)) << 3;
        short8 ahf = *(const short8*)&Ah[ar*64 + s];
        short8 alf = *(const short8*)&Al[ar*64 + s];
        #pragma unroll
        for (int ni = 0; ni < 2; ++ni) {
          acc[mi][ni] = __builtin_amdgcn_mfma_f32_16x16x32_bf16(ahf, bhf[ni], acc[mi][ni], 0,0,0);
          acc[mi][ni] = __builtin_amdgcn_mfma_f32_16x16x32_bf16(ahf, blf[ni], acc[mi][ni], 0,0,0);
          acc[mi][ni] = __builtin_amdgcn_mfma_f32_16x16x32_bf16(alf, bhf[ni], acc[mi][ni], 0,0,0);
        }
      }
    }
    __builtin_amdgcn_s_setprio(0);
  }
  __syncthreads();
  unsigned short* Trh = (unsigned short*)smem;
  unsigned short* Trl = Trh + 64*136;
  #pragma unroll
  for (int mi = 0; mi < 4; ++mi)
    #pragma unroll
    for (int ni = 0; ni < 2; ++ni)
      #pragma unroll
      for (int j = 0; j < 4; ++j) {
        int rloc = wr*64 + mi*16 + g*4 + j;
        int cloc = wc*32 + ni*16 + ln;
        float bias = (rloc < 64) ? bq[rloc] : bk[rloc - 64];
        unsigned short hi, lo; split_bf16(acc[mi][ni][j] + bias, hi, lo);
        Trh[cloc*136 + rloc] = hi;
        Trl[cloc*136 + rloc] = lo;
      }
  __syncthreads();
  #pragma unroll
  for (int i = 0; i < 4; ++i) {
    int idx = tid + i*256;
    int l = idx >> 4, s = idx & 15;
    long row = ((long)b*LSEQ + nt*64 + l) * 64;
    short8 h  = *(const short8*)&Trh[l*136 + s*8];
    short8 lo = *(const short8*)&Trl[l*136 + s*8];
    if (s < 8) { *(short8*)&qh[row + s*8] = h;      *(short8*)&ql[row + s*8] = lo; }
    else       { *(short8*)&kh[row + (s-8)*8] = h;  *(short8*)&kl[row + (s-8)*8] = lo; }
  }
}

// ---------- Kernel 2: v projection -> bf16 [b][c][l] ----------
// linear grid 1024, XCD-swizzled: all 32 tiles of batch b on XCD b%8.
__global__ __launch_bounds__(256, 2) void v_proj(
    const float* __restrict__ x,
    const unsigned short* __restrict__ Wvh,
    const float* __restrict__ bv,
    unsigned short* __restrict__ vws)
{
  const int gi = blockIdx.x;
  const int b  = (gi & 7) + 8 * (gi >> 8);
  const int t  = (gi >> 3) & 31;
  const int lt = t & 7, ct = t >> 3;
  const int tid = threadIdx.x;
  const int wave = tid >> 6, lane = tid & 63;
  const int wr = wave >> 1, wc = wave & 1;
  const int g = lane >> 4, ln = lane & 15;

  __shared__ char smem[66560];
  unsigned short* Ahs = (unsigned short*)smem;
  unsigned short* Bhs = Ahs + 8192;
  float* xs = (float*)(Bhs + 8192);

  f32x4 acc[4][4] = {};

  for (int kb = 0; kb < 8; ++kb) {
    if (kb) __syncthreads();
    #pragma unroll
    for (int i = 0; i < 4; ++i) {
      int idx = tid + i*256;
      int r = idx >> 3, jj = idx & 7;
      *(short8*)&Ahs[r*64 + ((jj ^ (r & 7)) << 3)] =
        *(const short8*)&Wvh[(ct*128 + r)*512 + kb*64 + jj*8];
    }
    #pragma unroll
    for (int i = 0; i < 8; ++i) {
      int idx = tid + i*256;
      int kk = idx >> 5, l4 = idx & 31;
      f32x4 v = *(const f32x4*)&x[((long)b*C_IN + kb*64 + kk)*LSEQ + lt*128 + l4*4];
      *(f32x4*)&xs[kk*132 + l4*4] = v;
    }
    __syncthreads();
    {
      int l = tid & 127, kc = (tid >> 7) * 32;
      unsigned short hbuf[32];
      #pragma unroll
      for (int i = 0; i < 32; ++i) hbuf[i] = bf16_rn(xs[(kc + i)*132 + l]);
      #pragma unroll
      for (int s2 = 0; s2 < 4; ++s2) {
        int s = (kc >> 3) + s2;
        *(short8*)&Bhs[l*64 + ((s ^ (l & 7)) << 3)] = *(const short8*)&hbuf[s2*8];
      }
    }
    __syncthreads();
    __builtin_amdgcn_s_setprio(1);
    #pragma unroll
    for (int ks = 0; ks < 2; ++ks) {
      short8 bf[4];
      #pragma unroll
      for (int ni = 0; ni < 4; ++ni) {
        int cr = wc*64 + ni*16 + ln;
        bf[ni] = *(const short8*)&Bhs[cr*64 + (((ks*4 + g) ^ (cr & 7)) << 3)];
      }
      #pragma unroll
      for (int mi = 0; mi < 4; ++mi) {
        int ar = wr*64 + mi*16 + ln;
        short8 af = *(const short8*)&Ahs[ar*64 + (((ks*4 + g) ^ (ar & 7)) << 3)];
        #pragma unroll
        for (int ni = 0; ni < 4; ++ni)
          acc[mi][ni] = __builtin_amdgcn_mfma_f32_16x16x32_bf16(af, bf[ni], acc[mi][ni], 0,0,0);
      }
    }
    __builtin_amdgcn_s_setprio(0);
  }
  __syncthreads();
  unsigned short* Tr = (unsigned short*)smem;
  #pragma unroll
  for (int mi = 0; mi < 4; ++mi)
    #pragma unroll
    for (int ni = 0; ni < 4; ++ni)
      #pragma unroll
      for (int j = 0; j < 4; ++j) {
        int rloc = wr*64 + mi*16 + g*4 + j;
        int cloc = wc*64 + ni*16 + ln;
        Tr[rloc*136 + cloc] = bf16_rn(acc[mi][ni][j] + bv[ct*128 + rloc]);
      }
  __syncthreads();
  #pragma unroll
  for (int i = 0; i < 8; ++i) {
    int idx = tid + i*256;
    int c = idx >> 4, s = idx & 15;
    *(short8*)&vws[((long)b*C_IN + ct*128 + c)*LSEQ + lt*128 + s*8] =
      *(const short8*)&Tr[c*136 + s*8];
  }
}

// ---------- Kernel 3: energy + softmax -> attn f32 (d_out) + P bf16 copy ----------
// linear grid 2048, XCD-swizzled: all 64 l-tiles of batch b on XCD b%8.
__global__ __launch_bounds__(256, 2) void energy_softmax(
    const unsigned short* __restrict__ qh, const unsigned short* __restrict__ ql,
    const unsigned short* __restrict__ kh, const unsigned short* __restrict__ kl,
    float* __restrict__ attn, unsigned short* __restrict__ pbuf)
{
  const int gi = blockIdx.x;
  const int b  = (gi & 7) + 8 * (gi >> 9);
  const int lt = (gi >> 3) & 63;
  const int tid = threadIdx.x;
  const int wave = tid >> 6, lane = tid & 63;
  const int g = lane >> 4, ln = lane & 15;

  __shared__ unsigned short Ksm[16640];
  __shared__ float redM[4][16];
  __shared__ float redS[4][16];
  unsigned short* Kh = Ksm;
  unsigned short* Kl = Ksm + 8192;

  short8 ah[2], al[2];
  {
    long qrow = ((long)b*LSEQ + lt*16 + ln) * 64;
    #pragma unroll
    for (int ks = 0; ks < 2; ++ks) {
      ah[ks] = *(const short8*)&qh[qrow + ks*32 + g*8];
      al[ks] = *(const short8*)&ql[qrow + ks*32 + g*8];
    }
  }

  const int rb = tid >> 3, jj = tid & 7;
  const int dst0 = rb*64 + ((jj ^ (rb & 7)) << 3);
  const long kbase = ((long)b*LSEQ + rb)*64 + jj*8;

  short8 rkh[4], rkl[4];
  #pragma unroll
  for (int j = 0; j < 4; ++j) {
    rkh[j] = *(const short8*)&kh[kbase + j*2048];
    rkl[j] = *(const short8*)&kl[kbase + j*2048];
  }

  f32x4 acc[8][2] = {};
  #pragma unroll
  for (int c = 0; c < 8; ++c) {
    __syncthreads();
    #pragma unroll
    for (int j = 0; j < 4; ++j) {
      *(short8*)&Kh[dst0 + j*2048] = rkh[j];
      *(short8*)&Kl[dst0 + j*2048] = rkl[j];
    }
    __syncthreads();
    if (c < 7) {
      #pragma unroll
      for (int j = 0; j < 4; ++j) {
        rkh[j] = *(const short8*)&kh[kbase + (long)(c+1)*8192 + j*2048];
        rkl[j] = *(const short8*)&kl[kbase + (long)(c+1)*8192 + j*2048];
      }
    }
    __builtin_amdgcn_s_setprio(1);
    #pragma unroll
    for (int fq = 0; fq < 2; ++fq) {
      int mloc = wave*32 + fq*16 + ln;
      #pragma unroll
      for (int ks = 0; ks < 2; ++ks) {
        int s = ((ks*4 + g) ^ (mloc & 7)) << 3;
        short8 bh = *(const short8*)&Kh[mloc*64 + s];
        short8 bl = *(const short8*)&Kl[mloc*64 + s];
        acc[c][fq] = __builtin_amdgcn_mfma_f32_16x16x32_bf16(ah[ks], bh, acc[c][fq], 0,0,0);
        acc[c][fq] = __builtin_amdgcn_mfma_f32_16x16x32_bf16(ah[ks], bl, acc[c][fq], 0,0,0);
        acc[c][fq] = __builtin_amdgcn_mfma_f32_16x16x32_bf16(al[ks], bh, acc[c][fq], 0,0,0);
      }
    }
    __builtin_amdgcn_s_setprio(0);
  }

  float mx[4];
  #pragma unroll
  for (int j = 0; j < 4; ++j) {
    float m = -1e30f;
    #pragma unroll
    for (int c = 0; c < 8; ++c)
      #pragma unroll
      for (int fq = 0; fq < 2; ++fq) m = fmaxf(m, acc[c][fq][j]);
    #pragma unroll
    for (int off = 1; off < 16; off <<= 1) m = fmaxf(m, __shfl_xor(m, off));
    mx[j] = m;
  }
  if (ln == 0) {
    #pragma unroll
    for (int j = 0; j < 4; ++j) redM[wave][g*4+j] = mx[j];
  }
  __syncthreads();
  #pragma unroll
  for (int j = 0; j < 4; ++j) {
    float m = redM[0][g*4+j];
    #pragma unroll
    for (int w = 1; w < 4; ++w) m = fmaxf(m, redM[w][g*4+j]);
    mx[j] = m;
  }
  float sm[4];
  #pragma unroll
  for (int j = 0; j < 4; ++j) {
    float s = 0.f;
    #pragma unroll
    for (int c = 0; c < 8; ++c)
      #pragma unroll
      for (int fq = 0; fq < 2; ++fq) {
        float p = __expf(acc[c][fq][j] - mx[j]);
        acc[c][fq][j] = p;
        s += p;
      }
    #pragma unroll
    for (int off = 1; off < 16; off <<= 1) s += __shfl_xor(s, off);
    sm[j] = s;
  }
  if (ln == 0) {
    #pragma unroll
    for (int j = 0; j < 4; ++j) redS[wave][g*4+j] = sm[j];
  }
  __syncthreads();
  #pragma unroll
  for (int j = 0; j < 4; ++j) {
    float s = redS[0][g*4+j];
    #pragma unroll
    for (int w = 1; w < 4; ++w) s += redS[w][g*4+j];
    sm[j] = 1.0f / s;
  }

  unsigned short* Pb = Ksm;              // [16][1032]
  __syncthreads();
  #pragma unroll
  for (int c = 0; c < 8; ++c)
    #pragma unroll
    for (int fq = 0; fq < 2; ++fq) {
      int m0 = c*128 + wave*32 + fq*16 + ln;
      #pragma unroll
      for (int j = 0; j < 4; ++j)
        Pb[(g*4+j)*1032 + m0] = bf16_rn(acc[c][fq][j] * sm[j]);
    }
  __syncthreads();
  #pragma unroll
  for (int u = 0; u < 8; ++u) {
    int cid = tid + u*256;
    int row = cid >> 7, col = (cid & 127) * 8;
    short8 v = *(const short8*)&Pb[row*1032 + col];
    long gro = ((long)b*LSEQ + lt*16 + row)*LSEQ + col;
    *(short8*)&pbuf[gro] = v;
    f32x4 f0, f1;
    #pragma unroll
    for (int i = 0; i < 4; ++i) {
      f0[i] = bf16_to_f32((unsigned short)v[i]);
      f1[i] = bf16_to_f32((unsigned short)v[i+4]);
    }
    *(f32x4*)&attn[gro] = f0;
    *(f32x4*)&attn[gro + 4] = f1;
  }
}

// ---------- Kernel 4: out = gamma * (V @ P^T) + x ----------
// 512 threads, 8 waves; tile 128c x 256l; linear grid 512, XCD-swizzled.
__global__ __launch_bounds__(512, 2) void pv_out(
    const unsigned short* __restrict__ vws,
    const unsigned short* __restrict__ pbuf,
    const float* __restrict__ x,
    const float* __restrict__ gamma,
    float* __restrict__ out)
{
  const int gi = blockIdx.x;             // 512 blocks: 16 per b, b -> XCD b%8
  const int b  = (gi & 7) + 8 * (gi >> 7);
  const int t  = (gi >> 3) & 15;
  const int lt = t >> 2, ct = t & 3;
  const int tid = threadIdx.x;
  const int w = tid >> 6, lane = tid & 63;
  const int wcq = w >> 2, wlq = w & 3;
  const int g = lane >> 4, ln = lane & 15;

  __shared__ char smem[49152];
  unsigned short* Vst = (unsigned short*)smem;            // [128][64] swz
  unsigned short* Pst = (unsigned short*)(smem + 16384);  // [256][64] swz

  const int vr = tid >> 2, vs0 = (tid & 3) * 2;
  const long vbase = ((long)b*C_IN + ct*128 + vr)*LSEQ + vs0*8;
  const int pr = tid >> 1, ps0 = (tid & 1) * 4;
  const long pbase = ((long)b*LSEQ + lt*256 + pr)*LSEQ + ps0*8;

  f32x4 acc[4][4] = {};
  short8 rv[2], rp[4];
  #pragma unroll
  for (int j = 0; j < 2; ++j) rv[j] = *(const short8*)&vws[vbase + j*8];
  #pragma unroll
  for (int j = 0; j < 4; ++j) rp[j] = *(const short8*)&pbuf[pbase + j*8];

  for (int mb = 0; mb < 16; ++mb) {
    __syncthreads();
    #pragma unroll
    for (int j = 0; j < 2; ++j)
      *(short8*)&Vst[vr*64 + (((vs0 + j) ^ (vr & 7)) << 3)] = rv[j];
    #pragma unroll
    for (int j = 0; j < 4; ++j)
      *(short8*)&Pst[pr*64 + (((ps0 + j) ^ (pr & 7)) << 3)] = rp[j];
    __syncthreads();
    if (mb < 15) {
      #pragma unroll
      for (int j = 0; j < 2; ++j) rv[j] = *(const short8*)&vws[vbase + (mb+1)*64 + j*8];
      #pragma unroll
      for (int j = 0; j < 4; ++j) rp[j] = *(const short8*)&pbuf[pbase + (mb+1)*64 + j*8];
    }
    __builtin_amdgcn_s_setprio(1);
    #pragma unroll
    for (int ks = 0; ks < 2; ++ks) {
      short8 bf[4];
      #pragma unroll
      for (int lf = 0; lf < 4; ++lf) {
        int prow = wlq*64 + lf*16 + ln;
        bf[lf] = *(const short8*)&Pst[prow*64 + (((ks*4 + g) ^ (prow & 7)) << 3)];
      }
      #pragma unroll
      for (int cf = 0; cf < 4; ++cf) {
        int cr = wcq*64 + cf*16 + ln;
        short8 af = *(const short8*)&Vst[cr*64 + (((ks*4 + g) ^ (cr & 7)) << 3)];
        #pragma unroll
        for (int lf = 0; lf < 4; ++lf)
          acc[cf][lf] = __builtin_amdgcn_mfma_f32_16x16x32_bf16(af, bf[lf], acc[cf][lf], 0,0,0);
      }
    }
    __builtin_amdgcn_s_setprio(0);
  }

  const float gm = gamma[0];
  #pragma unroll
  for (int cf = 0; cf < 4; ++cf)
    #pragma unroll
    for (int lf = 0; lf < 4; ++lf)
      #pragma unroll
      for (int j = 0; j < 4; ++j) {
        int c = ct*128 + wcq*64 + cf*16 + g*4 + j;
        int l = lt*256 + wlq*64 + lf*16 + ln;
        long o = ((long)b*C_IN + c)*LSEQ + l;
        out[o] = gm * acc[cf][lf][j] + x[o];
      }
}

extern "C" void kernel_launch(void* const* d_in, const int* in_sizes, int n_in,
                              void* d_out, int out_size, void* d_ws, size_t ws_size,
                              hipStream_t stream)
{
  const float* x  = (const float*)d_in[0];
  const float* Wq = (const float*)d_in[1];
  const float* bq = (const float*)d_in[2];
  const float* Wk = (const float*)d_in[3];
  const float* bk = (const float*)d_in[4];
  const float* Wv = (const float*)d_in[5];
  const float* bv = (const float*)d_in[6];
  const float* gamma = (const float*)d_in[7];
  float* out  = (float*)d_out;
  float* attn = out + OUT_ELEMS;

  char* ws = (char*)d_ws;
  unsigned short* Wqh = (unsigned short*)(ws + 0);
  unsigned short* Wql = (unsigned short*)(ws + 65536);
  unsigned short* Wkh = (unsigned short*)(ws + 131072);
  unsigned short* Wkl = (unsigned short*)(ws + 196608);
  unsigned short* Wvh = (unsigned short*)(ws + 262144);
  unsigned short* qhp = (unsigned short*)(ws + 786432);
  unsigned short* qlp = (unsigned short*)(ws + 786432 + 1ul*4194304);
  unsigned short* khp = (unsigned short*)(ws + 786432 + 2ul*4194304);
  unsigned short* klp = (unsigned short*)(ws + 786432 + 3ul*4194304);
  unsigned short* vws = (unsigned short*)(ws + 786432 + 4ul*4194304);
  unsigned short* pbuf = (unsigned short*)(ws + 786432 + 4ul*4194304 + 33554432);

  split_weights<<<320, 256, 0, stream>>>(Wq, Wk, Wv, Wqh, Wql, Wkh, Wkl, Wvh);
  qk_proj<<<dim3(16, B_SZ), 256, 0, stream>>>(x, Wqh, Wql, Wkh, Wkl, bq, bk, qhp, qlp, khp, klp);
  v_proj<<<1024, 256, 0, stream>>>(x, Wvh, bv, vws);
  energy_softmax<<<2048, 256, 0, stream>>>(qhp, qlp, khp, klp, attn, pbuf);
  pv_out<<<512, 512, 0, stream>>>(vws, pbuf, x, gamma, out);
}

// Round 10
// 183.606 us; speedup vs baseline: 1.3875x; 1.0377x over previous
//
#include <hip/hip_runtime.h>

typedef __attribute__((ext_vector_type(8))) short short8;
typedef __attribute__((ext_vector_type(4))) float f32x4;

#define B_SZ 32
#define C_IN 512
#define C8V 64
#define LSEQ 1024
#define OUT_ELEMS (B_SZ * C_IN * LSEQ)

__device__ inline unsigned short bf16_rn(float f) {
  unsigned int u = __float_as_uint(f);
  unsigned int r = 0x7FFFu + ((u >> 16) & 1u);
  return (unsigned short)((u + r) >> 16);
}
__device__ inline float bf16_to_f32(unsigned short h) {
  return __uint_as_float(((unsigned int)h) << 16);
}
__device__ inline void split_bf16(float f, unsigned short &hi, unsigned short &lo) {
  hi = bf16_rn(f);
  lo = bf16_rn(f - bf16_to_f32(hi));
}

// ---------- Kernel 0: pre-split weights into bf16 hi/lo planes ----------
__global__ __launch_bounds__(256) void split_weights(
    const float* __restrict__ Wq, const float* __restrict__ Wk, const float* __restrict__ Wv,
    unsigned short* __restrict__ Wqh, unsigned short* __restrict__ Wql,
    unsigned short* __restrict__ Wkh, unsigned short* __restrict__ Wkl,
    unsigned short* __restrict__ Wvh)
{
  int i = (blockIdx.x * 256 + threadIdx.x) * 4;
  if (i < 262144) {
    f32x4 f = *(const f32x4*)&Wv[i];
    #pragma unroll
    for (int j = 0; j < 4; ++j) Wvh[i + j] = bf16_rn(f[j]);
  } else if (i < 294912) {
    int k = i - 262144;
    f32x4 f = *(const f32x4*)&Wq[k];
    #pragma unroll
    for (int j = 0; j < 4; ++j) { unsigned short h, l; split_bf16(f[j], h, l); Wqh[k+j] = h; Wql[k+j] = l; }
  } else {
    int k = i - 294912;
    f32x4 f = *(const f32x4*)&Wk[k];
    #pragma unroll
    for (int j = 0; j < 4; ++j) { unsigned short h, l; split_bf16(f[j], h, l); Wkh[k+j] = h; Wkl[k+j] = l; }
  }
}

// ---------- Kernel 1: q,k projection -> pre-split [b][l][64] hi/lo planes ----------
// column-load transpose staging + reg prefetch. tile M=128(64q+64k) x N=64 l.
__global__ __launch_bounds__(256, 2) void qk_proj(
    const float* __restrict__ x,
    const unsigned short* __restrict__ Wqh, const unsigned short* __restrict__ Wql,
    const unsigned short* __restrict__ Wkh, const unsigned short* __restrict__ Wkl,
    const float* __restrict__ bq, const float* __restrict__ bk,
    unsigned short* __restrict__ qh, unsigned short* __restrict__ ql,
    unsigned short* __restrict__ kh, unsigned short* __restrict__ kl)
{
  const int nt = blockIdx.x;
  const int b  = blockIdx.y;
  const int tid = threadIdx.x;
  const int wave = tid >> 6, lane = tid & 63;
  const int wr = wave >> 1, wc = wave & 1;
  const int g = lane >> 4, ln = lane & 15;

  __shared__ char smem[49152];
  unsigned short* Ah = (unsigned short*)smem;      // [128][64] swz 16KB
  unsigned short* Al = Ah + 8192;                  // 16KB
  unsigned short* Bh = Al + 8192;                  // [64][64] swz 8KB
  unsigned short* Bl = Bh + 4096;                  // 8KB

  // A staging: rows rb + j*32 (j<2: Wq; j>=2: Wk), slot jj
  const int rb = tid >> 3, jj = tid & 7;
  const int adst0 = rb*64 + ((jj ^ (rb & 7)) << 3);
  // B staging: column xl, k-group xkg..xkg+15
  const int xl = tid & 63, xkg = (tid >> 6) * 16;
  const int bdst0 = xl*64 + (((xkg >> 3) ^ (xl & 7)) << 3);
  const long xcol = (long)b*C_IN*LSEQ + (long)nt*64 + xl;

  short8 rAh[4], rAl[4];
  float xv[16];
  rAh[0] = *(const short8*)&Wqh[rb*C_IN + jj*8];
  rAh[1] = *(const short8*)&Wqh[(rb+32)*C_IN + jj*8];
  rAh[2] = *(const short8*)&Wkh[rb*C_IN + jj*8];
  rAh[3] = *(const short8*)&Wkh[(rb+32)*C_IN + jj*8];
  rAl[0] = *(const short8*)&Wql[rb*C_IN + jj*8];
  rAl[1] = *(const short8*)&Wql[(rb+32)*C_IN + jj*8];
  rAl[2] = *(const short8*)&Wkl[rb*C_IN + jj*8];
  rAl[3] = *(const short8*)&Wkl[(rb+32)*C_IN + jj*8];
  #pragma unroll
  for (int i = 0; i < 16; ++i) xv[i] = x[xcol + (long)(xkg + i)*LSEQ];

  f32x4 acc[4][2] = {};

  for (int kb = 0; kb < 8; ++kb) {
    __syncthreads();
    #pragma unroll
    for (int j = 0; j < 4; ++j) {
      *(short8*)&Ah[adst0 + j*2048] = rAh[j];
      *(short8*)&Al[adst0 + j*2048] = rAl[j];
    }
    {
      unsigned short hb[16], lb[16];
      #pragma unroll
      for (int i = 0; i < 16; ++i) split_bf16(xv[i], hb[i], lb[i]);
      #pragma unroll
      for (int s2 = 0; s2 < 2; ++s2) {
        int d = xl*64 + ((((xkg >> 3) + s2) ^ (xl & 7)) << 3);
        *(short8*)&Bh[d] = *(const short8*)&hb[s2*8];
        *(short8*)&Bl[d] = *(const short8*)&lb[s2*8];
      }
    }
    __syncthreads();
    if (kb < 7) {
      int ko = (kb+1)*64;
      rAh[0] = *(const short8*)&Wqh[rb*C_IN + ko + jj*8];
      rAh[1] = *(const short8*)&Wqh[(rb+32)*C_IN + ko + jj*8];
      rAh[2] = *(const short8*)&Wkh[rb*C_IN + ko + jj*8];
      rAh[3] = *(const short8*)&Wkh[(rb+32)*C_IN + ko + jj*8];
      rAl[0] = *(const short8*)&Wql[rb*C_IN + ko + jj*8];
      rAl[1] = *(const short8*)&Wql[(rb+32)*C_IN + ko + jj*8];
      rAl[2] = *(const short8*)&Wkl[rb*C_IN + ko + jj*8];
      rAl[3] = *(const short8*)&Wkl[(rb+32)*C_IN + ko + jj*8];
      #pragma unroll
      for (int i = 0; i < 16; ++i) xv[i] = x[xcol + (long)(ko + xkg + i)*LSEQ];
    }
    __builtin_amdgcn_s_setprio(1);
    #pragma unroll
    for (int ks = 0; ks < 2; ++ks) {
      short8 bhf[2], blf[2];
      #pragma unroll
      for (int ni = 0; ni < 2; ++ni) {
        int cr = wc*32 + ni*16 + ln;
        int s = ((ks*4 + g) ^ (cr & 7)) << 3;
        bhf[ni] = *(const short8*)&Bh[cr*64 + s];
        blf[ni] = *(const short8*)&Bl[cr*64 + s];
      }
      #pragma unroll
      for (int mi = 0; mi < 4; ++mi) {
        int ar = wr*64 + mi*16 + ln;
        int s = ((ks*4 + g) ^ (ar & 7)) << 3;
        short8 ahf = *(const short8*)&Ah[ar*64 + s];
        short8 alf = *(const short8*)&Al[ar*64 + s];
        #pragma unroll
        for (int ni = 0; ni < 2; ++ni) {
          acc[mi][ni] = __builtin_amdgcn_mfma_f32_16x16x32_bf16(ahf, bhf[ni], acc[mi][ni], 0,0,0);
          acc[mi][ni] = __builtin_amdgcn_mfma_f32_16x16x32_bf16(ahf, blf[ni], acc[mi][ni], 0,0,0);
          acc[mi][ni] = __builtin_amdgcn_mfma_f32_16x16x32_bf16(alf, bhf[ni], acc[mi][ni], 0,0,0);
        }
      }
    }
    __builtin_amdgcn_s_setprio(0);
  }
  __syncthreads();
  unsigned short* Trh = (unsigned short*)smem;     // [64 l][136]
  unsigned short* Trl = Trh + 64*136;
  #pragma unroll
  for (int mi = 0; mi < 4; ++mi)
    #pragma unroll
    for (int ni = 0; ni < 2; ++ni)
      #pragma unroll
      for (int j = 0; j < 4; ++j) {
        int rloc = wr*64 + mi*16 + g*4 + j;
        int cloc = wc*32 + ni*16 + ln;
        float bias = (rloc < 64) ? bq[rloc] : bk[rloc - 64];
        unsigned short hi, lo; split_bf16(acc[mi][ni][j] + bias, hi, lo);
        Trh[cloc*136 + rloc] = hi;
        Trl[cloc*136 + rloc] = lo;
      }
  __syncthreads();
  #pragma unroll
  for (int i = 0; i < 4; ++i) {
    int idx = tid + i*256;
    int l = idx >> 4, s = idx & 15;
    long row = ((long)b*LSEQ + nt*64 + l) * 64;
    short8 h  = *(const short8*)&Trh[l*136 + s*8];
    short8 lo = *(const short8*)&Trl[l*136 + s*8];
    if (s < 8) { *(short8*)&qh[row + s*8] = h;      *(short8*)&ql[row + s*8] = lo; }
    else       { *(short8*)&kh[row + (s-8)*8] = h;  *(short8*)&kl[row + (s-8)*8] = lo; }
  }
}

// ---------- Kernel 2: v projection -> bf16 [b][c][l] ----------
// column-load transpose staging + reg prefetch; linear grid 1024, XCD-swizzled.
__global__ __launch_bounds__(256, 2) void v_proj(
    const float* __restrict__ x,
    const unsigned short* __restrict__ Wvh,
    const float* __restrict__ bv,
    unsigned short* __restrict__ vws)
{
  const int gi = blockIdx.x;
  const int b  = (gi & 7) + 8 * (gi >> 8);
  const int t  = (gi >> 3) & 31;
  const int lt = t & 7, ct = t >> 3;
  const int tid = threadIdx.x;
  const int wave = tid >> 6, lane = tid & 63;
  const int wr = wave >> 1, wc = wave & 1;
  const int g = lane >> 4, ln = lane & 15;

  __shared__ char smem[34816];
  unsigned short* Ahs = (unsigned short*)smem;     // [128][64] swz 16KB
  unsigned short* Bhs = Ahs + 8192;                // [128][64] swz 16KB

  const int rb = tid >> 3, jj = tid & 7;
  const int adst0 = rb*64 + ((jj ^ (rb & 7)) << 3);
  const long wbase = (long)(ct*128 + rb)*C_IN + jj*8;
  const int xl = tid & 127, xkg = (tid >> 7) * 32;
  const long xcol = (long)b*C_IN*LSEQ + (long)lt*128 + xl;

  short8 rA[4];
  float xv[32];
  #pragma unroll
  for (int j = 0; j < 4; ++j) rA[j] = *(const short8*)&Wvh[wbase + (long)j*32*C_IN];
  #pragma unroll
  for (int i = 0; i < 32; ++i) xv[i] = x[xcol + (long)(xkg + i)*LSEQ];

  f32x4 acc[4][4] = {};

  for (int kb = 0; kb < 8; ++kb) {
    __syncthreads();
    #pragma unroll
    for (int j = 0; j < 4; ++j)
      *(short8*)&Ahs[adst0 + j*2048] = rA[j];
    {
      unsigned short hb[32];
      #pragma unroll
      for (int i = 0; i < 32; ++i) hb[i] = bf16_rn(xv[i]);
      #pragma unroll
      for (int s2 = 0; s2 < 4; ++s2) {
        int d = xl*64 + ((((xkg >> 3) + s2) ^ (xl & 7)) << 3);
        *(short8*)&Bhs[d] = *(const short8*)&hb[s2*8];
      }
    }
    __syncthreads();
    if (kb < 7) {
      int ko = (kb+1)*64;
      #pragma unroll
      for (int j = 0; j < 4; ++j) rA[j] = *(const short8*)&Wvh[wbase + (long)j*32*C_IN + ko];
      #pragma unroll
      for (int i = 0; i < 32; ++i) xv[i] = x[xcol + (long)(ko + xkg + i)*LSEQ];
    }
    __builtin_amdgcn_s_setprio(1);
    #pragma unroll
    for (int ks = 0; ks < 2; ++ks) {
      short8 bf[4];
      #pragma unroll
      for (int ni = 0; ni < 4; ++ni) {
        int cr = wc*64 + ni*16 + ln;
        bf[ni] = *(const short8*)&Bhs[cr*64 + (((ks*4 + g) ^ (cr & 7)) << 3)];
      }
      #pragma unroll
      for (int mi = 0; mi < 4; ++mi) {
        int ar = wr*64 + mi*16 + ln;
        short8 af = *(const short8*)&Ahs[ar*64 + (((ks*4 + g) ^ (ar & 7)) << 3)];
        #pragma unroll
        for (int ni = 0; ni < 4; ++ni)
          acc[mi][ni] = __builtin_amdgcn_mfma_f32_16x16x32_bf16(af, bf[ni], acc[mi][ni], 0,0,0);
      }
    }
    __builtin_amdgcn_s_setprio(0);
  }
  __syncthreads();
  unsigned short* Tr = (unsigned short*)smem;      // [128 c][136]
  #pragma unroll
  for (int mi = 0; mi < 4; ++mi)
    #pragma unroll
    for (int ni = 0; ni < 4; ++ni)
      #pragma unroll
      for (int j = 0; j < 4; ++j) {
        int rloc = wr*64 + mi*16 + g*4 + j;
        int cloc = wc*64 + ni*16 + ln;
        Tr[rloc*136 + cloc] = bf16_rn(acc[mi][ni][j] + bv[ct*128 + rloc]);
      }
  __syncthreads();
  #pragma unroll
  for (int i = 0; i < 8; ++i) {
    int idx = tid + i*256;
    int c = idx >> 4, s = idx & 15;
    *(short8*)&vws[((long)b*C_IN + ct*128 + c)*LSEQ + lt*128 + s*8] =
      *(const short8*)&Tr[c*136 + s*8];
  }
}

// ---------- Kernel 3: energy + softmax -> attn f32 (d_out) + P bf16 copy ----------
__global__ __launch_bounds__(256, 2) void energy_softmax(
    const unsigned short* __restrict__ qh, const unsigned short* __restrict__ ql,
    const unsigned short* __restrict__ kh, const unsigned short* __restrict__ kl,
    float* __restrict__ attn, unsigned short* __restrict__ pbuf)
{
  const int gi = blockIdx.x;
  const int b  = (gi & 7) + 8 * (gi >> 9);
  const int lt = (gi >> 3) & 63;
  const int tid = threadIdx.x;
  const int wave = tid >> 6, lane = tid & 63;
  const int g = lane >> 4, ln = lane & 15;

  __shared__ unsigned short Ksm[16640];
  __shared__ float redM[4][16];
  __shared__ float redS[4][16];
  unsigned short* Kh = Ksm;
  unsigned short* Kl = Ksm + 8192;

  short8 ah[2], al[2];
  {
    long qrow = ((long)b*LSEQ + lt*16 + ln) * 64;
    #pragma unroll
    for (int ks = 0; ks < 2; ++ks) {
      ah[ks] = *(const short8*)&qh[qrow + ks*32 + g*8];
      al[ks] = *(const short8*)&ql[qrow + ks*32 + g*8];
    }
  }

  const int rb = tid >> 3, jj = tid & 7;
  const int dst0 = rb*64 + ((jj ^ (rb & 7)) << 3);
  const long kbase = ((long)b*LSEQ + rb)*64 + jj*8;

  short8 rkh[4], rkl[4];
  #pragma unroll
  for (int j = 0; j < 4; ++j) {
    rkh[j] = *(const short8*)&kh[kbase + j*2048];
    rkl[j] = *(const short8*)&kl[kbase + j*2048];
  }

  f32x4 acc[8][2] = {};
  #pragma unroll
  for (int c = 0; c < 8; ++c) {
    __syncthreads();
    #pragma unroll
    for (int j = 0; j < 4; ++j) {
      *(short8*)&Kh[dst0 + j*2048] = rkh[j];
      *(short8*)&Kl[dst0 + j*2048] = rkl[j];
    }
    __syncthreads();
    if (c < 7) {
      #pragma unroll
      for (int j = 0; j < 4; ++j) {
        rkh[j] = *(const short8*)&kh[kbase + (long)(c+1)*8192 + j*2048];
        rkl[j] = *(const short8*)&kl[kbase + (long)(c+1)*8192 + j*2048];
      }
    }
    __builtin_amdgcn_s_setprio(1);
    #pragma unroll
    for (int fq = 0; fq < 2; ++fq) {
      int mloc = wave*32 + fq*16 + ln;
      #pragma unroll
      for (int ks = 0; ks < 2; ++ks) {
        int s = ((ks*4 + g) ^ (mloc & 7)) << 3;
        short8 bh = *(const short8*)&Kh[mloc*64 + s];
        short8 bl = *(const short8*)&Kl[mloc*64 + s];
        acc[c][fq] = __builtin_amdgcn_mfma_f32_16x16x32_bf16(ah[ks], bh, acc[c][fq], 0,0,0);
        acc[c][fq] = __builtin_amdgcn_mfma_f32_16x16x32_bf16(ah[ks], bl, acc[c][fq], 0,0,0);
        acc[c][fq] = __builtin_amdgcn_mfma_f32_16x16x32_bf16(al[ks], bh, acc[c][fq], 0,0,0);
      }
    }
    __builtin_amdgcn_s_setprio(0);
  }

  float mx[4];
  #pragma unroll
  for (int j = 0; j < 4; ++j) {
    float m = -1e30f;
    #pragma unroll
    for (int c = 0; c < 8; ++c)
      #pragma unroll
      for (int fq = 0; fq < 2; ++fq) m = fmaxf(m, acc[c][fq][j]);
    #pragma unroll
    for (int off = 1; off < 16; off <<= 1) m = fmaxf(m, __shfl_xor(m, off));
    mx[j] = m;
  }
  if (ln == 0) {
    #pragma unroll
    for (int j = 0; j < 4; ++j) redM[wave][g*4+j] = mx[j];
  }
  __syncthreads();
  #pragma unroll
  for (int j = 0; j < 4; ++j) {
    float m = redM[0][g*4+j];
    #pragma unroll
    for (int w = 1; w < 4; ++w) m = fmaxf(m, redM[w][g*4+j]);
    mx[j] = m;
  }
  float sm[4];
  #pragma unroll
  for (int j = 0; j < 4; ++j) {
    float s = 0.f;
    #pragma unroll
    for (int c = 0; c < 8; ++c)
      #pragma unroll
      for (int fq = 0; fq < 2; ++fq) {
        float p = __expf(acc[c][fq][j] - mx[j]);
        acc[c][fq][j] = p;
        s += p;
      }
    #pragma unroll
    for (int off = 1; off < 16; off <<= 1) s += __shfl_xor(s, off);
    sm[j] = s;
  }
  if (ln == 0) {
    #pragma unroll
    for (int j = 0; j < 4; ++j) redS[wave][g*4+j] = sm[j];
  }
  __syncthreads();
  #pragma unroll
  for (int j = 0; j < 4; ++j) {
    float s = redS[0][g*4+j];
    #pragma unroll
    for (int w = 1; w < 4; ++w) s += redS[w][g*4+j];
    sm[j] = 1.0f / s;
  }

  unsigned short* Pb = Ksm;              // [16][1032]
  __syncthreads();
  #pragma unroll
  for (int c = 0; c < 8; ++c)
    #pragma unroll
    for (int fq = 0; fq < 2; ++fq) {
      int m0 = c*128 + wave*32 + fq*16 + ln;
      #pragma unroll
      for (int j = 0; j < 4; ++j)
        Pb[(g*4+j)*1032 + m0] = bf16_rn(acc[c][fq][j] * sm[j]);
    }
  __syncthreads();
  #pragma unroll
  for (int u = 0; u < 8; ++u) {
    int cid = tid + u*256;
    int row = cid >> 7, col = (cid & 127) * 8;
    short8 v = *(const short8*)&Pb[row*1032 + col];
    long gro = ((long)b*LSEQ + lt*16 + row)*LSEQ + col;
    *(short8*)&pbuf[gro] = v;
    f32x4 f0, f1;
    #pragma unroll
    for (int i = 0; i < 4; ++i) {
      f0[i] = bf16_to_f32((unsigned short)v[i]);
      f1[i] = bf16_to_f32((unsigned short)v[i+4]);
    }
    *(f32x4*)&attn[gro] = f0;
    *(f32x4*)&attn[gro + 4] = f1;
  }
}

// ---------- Kernel 4: out = gamma * (V @ P^T) + x ----------
__global__ __launch_bounds__(512, 2) void pv_out(
    const unsigned short* __restrict__ vws,
    const unsigned short* __restrict__ pbuf,
    const float* __restrict__ x,
    const float* __restrict__ gamma,
    float* __restrict__ out)
{
  const int gi = blockIdx.x;
  const int b  = (gi & 7) + 8 * (gi >> 7);
  const int t  = (gi >> 3) & 15;
  const int lt = t >> 2, ct = t & 3;
  const int tid = threadIdx.x;
  const int w = tid >> 6, lane = tid & 63;
  const int wcq = w >> 2, wlq = w & 3;
  const int g = lane >> 4, ln = lane & 15;

  __shared__ char smem[49152];
  unsigned short* Vst = (unsigned short*)smem;            // [128][64] swz
  unsigned short* Pst = (unsigned short*)(smem + 16384);  // [256][64] swz

  const int vr = tid >> 2, vs0 = (tid & 3) * 2;
  const long vbase = ((long)b*C_IN + ct*128 + vr)*LSEQ + vs0*8;
  const int pr = tid >> 1, ps0 = (tid & 1) * 4;
  const long pbase = ((long)b*LSEQ + lt*256 + pr)*LSEQ + ps0*8;

  f32x4 acc[4][4] = {};
  short8 rv[2], rp[4];
  #pragma unroll
  for (int j = 0; j < 2; ++j) rv[j] = *(const short8*)&vws[vbase + j*8];
  #pragma unroll
  for (int j = 0; j < 4; ++j) rp[j] = *(const short8*)&pbuf[pbase + j*8];

  for (int mb = 0; mb < 16; ++mb) {
    __syncthreads();
    #pragma unroll
    for (int j = 0; j < 2; ++j)
      *(short8*)&Vst[vr*64 + (((vs0 + j) ^ (vr & 7)) << 3)] = rv[j];
    #pragma unroll
    for (int j = 0; j < 4; ++j)
      *(short8*)&Pst[pr*64 + (((ps0 + j) ^ (pr & 7)) << 3)] = rp[j];
    __syncthreads();
    if (mb < 15) {
      #pragma unroll
      for (int j = 0; j < 2; ++j) rv[j] = *(const short8*)&vws[vbase + (mb+1)*64 + j*8];
      #pragma unroll
      for (int j = 0; j < 4; ++j) rp[j] = *(const short8*)&pbuf[pbase + (mb+1)*64 + j*8];
    }
    __builtin_amdgcn_s_setprio(1);
    #pragma unroll
    for (int ks = 0; ks < 2; ++ks) {
      short8 bf[4];
      #pragma unroll
      for (int lf = 0; lf < 4; ++lf) {
        int prow = wlq*64 + lf*16 + ln;
        bf[lf] = *(const short8*)&Pst[prow*64 + (((ks*4 + g) ^ (prow & 7)) << 3)];
      }
      #pragma unroll
      for (int cf = 0; cf < 4; ++cf) {
        int cr = wcq*64 + cf*16 + ln;
        short8 af = *(const short8*)&Vst[cr*64 + (((ks*4 + g) ^ (cr & 7)) << 3)];
        #pragma unroll
        for (int lf = 0; lf < 4; ++lf)
          acc[cf][lf] = __builtin_amdgcn_mfma_f32_16x16x32_bf16(af, bf[lf], acc[cf][lf], 0,0,0);
      }
    }
    __builtin_amdgcn_s_setprio(0);
  }

  const float gm = gamma[0];
  #pragma unroll
  for (int cf = 0; cf < 4; ++cf)
    #pragma unroll
    for (int lf = 0; lf < 4; ++lf)
      #pragma unroll
      for (int j = 0; j < 4; ++j) {
        int c = ct*128 + wcq*64 + cf*16 + g*4 + j;
        int l = lt*256 + wlq*64 + lf*16 + ln;
        long o = ((long)b*C_IN + c)*LSEQ + l;
        out[o] = gm * acc[cf][lf][j] + x[o];
      }
}

extern "C" void kernel_launch(void* const* d_in, const int* in_sizes, int n_in,
                              void* d_out, int out_size, void* d_ws, size_t ws_size,
                              hipStream_t stream)
{
  const float* x  = (const float*)d_in[0];
  const float* Wq = (const float*)d_in[1];
  const float* bq = (const float*)d_in[2];
  const float* Wk = (const float*)d_in[3];
  const float* bk = (const float*)d_in[4];
  const float* Wv = (const float*)d_in[5];
  const float* bv = (const float*)d_in[6];
  const float* gamma = (const float*)d_in[7];
  float* out  = (float*)d_out;
  float* attn = out + OUT_ELEMS;

  char* ws = (char*)d_ws;
  unsigned short* Wqh = (unsigned short*)(ws + 0);
  unsigned short* Wql = (unsigned short*)(ws + 65536);
  unsigned short* Wkh = (unsigned short*)(ws + 131072);
  unsigned short* Wkl = (unsigned short*)(ws + 196608);
  unsigned short* Wvh = (unsigned short*)(ws + 262144);
  unsigned short* qhp = (unsigned short*)(ws + 786432);
  unsigned short* qlp = (unsigned short*)(ws + 786432 + 1ul*4194304);
  unsigned short* khp = (unsigned short*)(ws + 786432 + 2ul*4194304);
  unsigned short* klp = (unsigned short*)(ws + 786432 + 3ul*4194304);
  unsigned short* vws = (unsigned short*)(ws + 786432 + 4ul*4194304);
  unsigned short* pbuf = (unsigned short*)(ws + 786432 + 4ul*4194304 + 33554432);

  split_weights<<<320, 256, 0, stream>>>(Wq, Wk, Wv, Wqh, Wql, Wkh, Wkl, Wvh);
  qk_proj<<<dim3(16, B_SZ), 256, 0, stream>>>(x, Wqh, Wql, Wkh, Wkl, bq, bk, qhp, qlp, khp, klp);
  v_proj<<<1024, 256, 0, stream>>>(x, Wvh, bv, vws);
  energy_softmax<<<2048, 256, 0, stream>>>(qhp, qlp, khp, klp, attn, pbuf);
  pv_out<<<512, 512, 0, stream>>>(vws, pbuf, x, gamma, out);
}

// Round 12
// 175.877 us; speedup vs baseline: 1.4484x; 1.0439x over previous
//
#include <hip/hip_runtime.h>

typedef __attribute__((ext_vector_type(8))) short short8;
typedef __attribute__((ext_vector_type(4))) float f32x4;

#define B_SZ 32
#define C_IN 512
#define C8V 64
#define LSEQ 1024
#define OUT_ELEMS (B_SZ * C_IN * LSEQ)

__device__ inline unsigned short bf16_rn(float f) {
  unsigned int u = __float_as_uint(f);
  unsigned int r = 0x7FFFu + ((u >> 16) & 1u);
  return (unsigned short)((u + r) >> 16);
}
__device__ inline float bf16_to_f32(unsigned short h) {
  return __uint_as_float(((unsigned int)h) << 16);
}
__device__ inline void split_bf16(float f, unsigned short &hi, unsigned short &lo) {
  hi = bf16_rn(f);
  lo = bf16_rn(f - bf16_to_f32(hi));
}

// ---------- Kernel 0: pre-split weights into bf16 hi/lo planes ----------
__global__ __launch_bounds__(256) void split_weights(
    const float* __restrict__ Wq, const float* __restrict__ Wk, const float* __restrict__ Wv,
    unsigned short* __restrict__ Wqh, unsigned short* __restrict__ Wql,
    unsigned short* __restrict__ Wkh, unsigned short* __restrict__ Wkl,
    unsigned short* __restrict__ Wvh)
{
  int i = (blockIdx.x * 256 + threadIdx.x) * 4;
  if (i < 262144) {
    f32x4 f = *(const f32x4*)&Wv[i];
    #pragma unroll
    for (int j = 0; j < 4; ++j) Wvh[i + j] = bf16_rn(f[j]);
  } else if (i < 294912) {
    int k = i - 262144;
    f32x4 f = *(const f32x4*)&Wq[k];
    #pragma unroll
    for (int j = 0; j < 4; ++j) { unsigned short h, l; split_bf16(f[j], h, l); Wqh[k+j] = h; Wql[k+j] = l; }
  } else {
    int k = i - 294912;
    f32x4 f = *(const f32x4*)&Wk[k];
    #pragma unroll
    for (int j = 0; j < 4; ++j) { unsigned short h, l; split_bf16(f[j], h, l); Wkh[k+j] = h; Wkl[k+j] = l; }
  }
}

// ---------- Kernel 1 (merged): q,k projection (blocks 0..511) + v projection (512..1535) ----------
__global__ __launch_bounds__(256, 2) void proj(
    const float* __restrict__ x,
    const unsigned short* __restrict__ Wqh, const unsigned short* __restrict__ Wql,
    const unsigned short* __restrict__ Wkh, const unsigned short* __restrict__ Wkl,
    const unsigned short* __restrict__ Wvh,
    const float* __restrict__ bq, const float* __restrict__ bk,
    const float* __restrict__ bv,
    unsigned short* __restrict__ qh, unsigned short* __restrict__ ql,
    unsigned short* __restrict__ kh, unsigned short* __restrict__ kl,
    unsigned short* __restrict__ vws)
{
  __shared__ char smem[49152];
  const int tid = threadIdx.x;
  const int wave = tid >> 6, lane = tid & 63;
  const int wr = wave >> 1, wc = wave & 1;
  const int g = lane >> 4, ln = lane & 15;

  if (blockIdx.x < 512) {
    // ================= q,k projection: tile M=128(64q+64k) x N=64 l =================
    const int gi = blockIdx.x;
    const int b  = (gi & 7) + 8 * (gi >> 7);
    const int nt = (gi >> 3) & 15;

    unsigned short* Ah = (unsigned short*)smem;      // [128][64] swz
    unsigned short* Al = Ah + 8192;
    unsigned short* Bh = Al + 8192;                  // [64][64] swz
    unsigned short* Bl = Bh + 4096;

    const int rb = tid >> 3, jj = tid & 7;
    const int adst0 = rb*64 + ((jj ^ (rb & 7)) << 3);
    const int xl = tid & 63, xkg = (tid >> 6) * 16;
    const long xcol = (long)b*C_IN*LSEQ + (long)nt*64 + xl;

    short8 rAh[4], rAl[4];
    float xv[16];
    rAh[0] = *(const short8*)&Wqh[rb*C_IN + jj*8];
    rAh[1] = *(const short8*)&Wqh[(rb+32)*C_IN + jj*8];
    rAh[2] = *(const short8*)&Wkh[rb*C_IN + jj*8];
    rAh[3] = *(const short8*)&Wkh[(rb+32)*C_IN + jj*8];
    rAl[0] = *(const short8*)&Wql[rb*C_IN + jj*8];
    rAl[1] = *(const short8*)&Wql[(rb+32)*C_IN + jj*8];
    rAl[2] = *(const short8*)&Wkl[rb*C_IN + jj*8];
    rAl[3] = *(const short8*)&Wkl[(rb+32)*C_IN + jj*8];
    #pragma unroll
    for (int i = 0; i < 16; ++i) xv[i] = x[xcol + (long)(xkg + i)*LSEQ];

    f32x4 acc[4][2] = {};

    for (int kb = 0; kb < 8; ++kb) {
      __syncthreads();
      #pragma unroll
      for (int j = 0; j < 4; ++j) {
        *(short8*)&Ah[adst0 + j*2048] = rAh[j];
        *(short8*)&Al[adst0 + j*2048] = rAl[j];
      }
      {
        unsigned short hb[16], lb[16];
        #pragma unroll
        for (int i = 0; i < 16; ++i) split_bf16(xv[i], hb[i], lb[i]);
        #pragma unroll
        for (int s2 = 0; s2 < 2; ++s2) {
          int d = xl*64 + ((((xkg >> 3) + s2) ^ (xl & 7)) << 3);
          *(short8*)&Bh[d] = *(const short8*)&hb[s2*8];
          *(short8*)&Bl[d] = *(const short8*)&lb[s2*8];
        }
      }
      __syncthreads();
      if (kb < 7) {
        int ko = (kb+1)*64;
        rAh[0] = *(const short8*)&Wqh[rb*C_IN + ko + jj*8];
        rAh[1] = *(const short8*)&Wqh[(rb+32)*C_IN + ko + jj*8];
        rAh[2] = *(const short8*)&Wkh[rb*C_IN + ko + jj*8];
        rAh[3] = *(const short8*)&Wkh[(rb+32)*C_IN + ko + jj*8];
        rAl[0] = *(const short8*)&Wql[rb*C_IN + ko + jj*8];
        rAl[1] = *(const short8*)&Wql[(rb+32)*C_IN + ko + jj*8];
        rAl[2] = *(const short8*)&Wkl[rb*C_IN + ko + jj*8];
        rAl[3] = *(const short8*)&Wkl[(rb+32)*C_IN + ko + jj*8];
        #pragma unroll
        for (int i = 0; i < 16; ++i) xv[i] = x[xcol + (long)(ko + xkg + i)*LSEQ];
      }
      __builtin_amdgcn_s_setprio(1);
      #pragma unroll
      for (int ks = 0; ks < 2; ++ks) {
        short8 bhf[2], blf[2];
        #pragma unroll
        for (int ni = 0; ni < 2; ++ni) {
          int cr = wc*32 + ni*16 + ln;
          int s = ((ks*4 + g) ^ (cr & 7)) << 3;
          bhf[ni] = *(const short8*)&Bh[cr*64 + s];
          blf[ni] = *(const short8*)&Bl[cr*64 + s];
        }
        #pragma unroll
        for (int mi = 0; mi < 4; ++mi) {
          int ar = wr*64 + mi*16 + ln;
          int s = ((ks*4 + g) ^ (ar & 7)) << 3;
          short8 ahf = *(const short8*)&Ah[ar*64 + s];
          short8 alf = *(const short8*)&Al[ar*64 + s];
          #pragma unroll
          for (int ni = 0; ni < 2; ++ni) {
            acc[mi][ni] = __builtin_amdgcn_mfma_f32_16x16x32_bf16(ahf, bhf[ni], acc[mi][ni], 0,0,0);
            acc[mi][ni] = __builtin_amdgcn_mfma_f32_16x16x32_bf16(ahf, blf[ni], acc[mi][ni], 0,0,0);
            acc[mi][ni] = __builtin_amdgcn_mfma_f32_16x16x32_bf16(alf, bhf[ni], acc[mi][ni], 0,0,0);
          }
        }
      }
      __builtin_amdgcn_s_setprio(0);
    }
    __syncthreads();
    unsigned short* Trh = (unsigned short*)smem;     // [64 l][136]
    unsigned short* Trl = Trh + 64*136;
    #pragma unroll
    for (int mi = 0; mi < 4; ++mi)
      #pragma unroll
      for (int ni = 0; ni < 2; ++ni)
        #pragma unroll
        for (int j = 0; j < 4; ++j) {
          int rloc = wr*64 + mi*16 + g*4 + j;
          int cloc = wc*32 + ni*16 + ln;
          float bias = (rloc < 64) ? bq[rloc] : bk[rloc - 64];
          unsigned short hi, lo; split_bf16(acc[mi][ni][j] + bias, hi, lo);
          Trh[cloc*136 + rloc] = hi;
          Trl[cloc*136 + rloc] = lo;
        }
    __syncthreads();
    #pragma unroll
    for (int i = 0; i < 4; ++i) {
      int idx = tid + i*256;
      int l = idx >> 4, s = idx & 15;
      long row = ((long)b*LSEQ + nt*64 + l) * 64;
      short8 h  = *(const short8*)&Trh[l*136 + s*8];
      short8 lo = *(const short8*)&Trl[l*136 + s*8];
      if (s < 8) { *(short8*)&qh[row + s*8] = h;      *(short8*)&ql[row + s*8] = lo; }
      else       { *(short8*)&kh[row + (s-8)*8] = h;  *(short8*)&kl[row + (s-8)*8] = lo; }
    }
  } else {
    // ================= v projection: tile 128c x 128l =================
    const int gj = blockIdx.x - 512;
    const int b  = (gj & 7) + 8 * (gj >> 8);
    const int t  = (gj >> 3) & 31;
    const int lt = t & 7, ct = t >> 3;

    unsigned short* Ahs = (unsigned short*)smem;     // [128][64] swz
    unsigned short* Bhs = Ahs + 8192;                // [128][64] swz

    const int rb = tid >> 3, jj = tid & 7;
    const int adst0 = rb*64 + ((jj ^ (rb & 7)) << 3);
    const long wbase = (long)(ct*128 + rb)*C_IN + jj*8;
    const int xl = tid & 127, xkg = (tid >> 7) * 32;
    const long xcol = (long)b*C_IN*LSEQ + (long)lt*128 + xl;

    short8 rA[4];
    float xv[32];
    #pragma unroll
    for (int j = 0; j < 4; ++j) rA[j] = *(const short8*)&Wvh[wbase + (long)j*32*C_IN];
    #pragma unroll
    for (int i = 0; i < 32; ++i) xv[i] = x[xcol + (long)(xkg + i)*LSEQ];

    f32x4 acc[4][4] = {};

    for (int kb = 0; kb < 8; ++kb) {
      __syncthreads();
      #pragma unroll
      for (int j = 0; j < 4; ++j)
        *(short8*)&Ahs[adst0 + j*2048] = rA[j];
      {
        unsigned short hb[32];
        #pragma unroll
        for (int i = 0; i < 32; ++i) hb[i] = bf16_rn(xv[i]);
        #pragma unroll
        for (int s2 = 0; s2 < 4; ++s2) {
          int d = xl*64 + ((((xkg >> 3) + s2) ^ (xl & 7)) << 3);
          *(short8*)&Bhs[d] = *(const short8*)&hb[s2*8];
        }
      }
      __syncthreads();
      if (kb < 7) {
        int ko = (kb+1)*64;
        #pragma unroll
        for (int j = 0; j < 4; ++j) rA[j] = *(const short8*)&Wvh[wbase + (long)j*32*C_IN + ko];
        #pragma unroll
        for (int i = 0; i < 32; ++i) xv[i] = x[xcol + (long)(ko + xkg + i)*LSEQ];
      }
      __builtin_amdgcn_s_setprio(1);
      #pragma unroll
      for (int ks = 0; ks < 2; ++ks) {
        short8 bf[4];
        #pragma unroll
        for (int ni = 0; ni < 4; ++ni) {
          int cr = wc*64 + ni*16 + ln;
          bf[ni] = *(const short8*)&Bhs[cr*64 + (((ks*4 + g) ^ (cr & 7)) << 3)];
        }
        #pragma unroll
        for (int mi = 0; mi < 4; ++mi) {
          int ar = wr*64 + mi*16 + ln;
          short8 af = *(const short8*)&Ahs[ar*64 + (((ks*4 + g) ^ (ar & 7)) << 3)];
          #pragma unroll
          for (int ni = 0; ni < 4; ++ni)
            acc[mi][ni] = __builtin_amdgcn_mfma_f32_16x16x32_bf16(af, bf[ni], acc[mi][ni], 0,0,0);
        }
      }
      __builtin_amdgcn_s_setprio(0);
    }
    __syncthreads();
    unsigned short* Tr = (unsigned short*)smem;      // [128 c][136]
    #pragma unroll
    for (int mi = 0; mi < 4; ++mi)
      #pragma unroll
      for (int ni = 0; ni < 4; ++ni)
        #pragma unroll
        for (int j = 0; j < 4; ++j) {
          int rloc = wr*64 + mi*16 + g*4 + j;
          int cloc = wc*64 + ni*16 + ln;
          Tr[rloc*136 + cloc] = bf16_rn(acc[mi][ni][j] + bv[ct*128 + rloc]);
        }
    __syncthreads();
    #pragma unroll
    for (int i = 0; i < 8; ++i) {
      int idx = tid + i*256;
      int c = idx >> 4, s = idx & 15;
      *(short8*)&vws[((long)b*C_IN + ct*128 + c)*LSEQ + lt*128 + s*8] =
        *(const short8*)&Tr[c*136 + s*8];
    }
  }
}

// ---------- Kernel 3: energy + softmax -> attn f32 (d_out) + P bf16 copy ----------
// 32 rows/block; linear grid 1024, XCD-swizzled: 32 blocks of b on XCD b%8.
__global__ __launch_bounds__(256, 2) void energy_softmax(
    const unsigned short* __restrict__ qh, const unsigned short* __restrict__ ql,
    const unsigned short* __restrict__ kh, const unsigned short* __restrict__ kl,
    float* __restrict__ attn, unsigned short* __restrict__ pbuf)
{
  const int gi = blockIdx.x;
  const int b  = (gi & 7) + 8 * (gi >> 8);
  const int lt = (gi >> 3) & 31;
  const int tid = threadIdx.x;
  const int wave = tid >> 6, lane = tid & 63;
  const int g = lane >> 4, ln = lane & 15;

  __shared__ unsigned short Ksm[33024];   // K: hi[8192]+lo[8192]; reused as Pb[32][1032]
  __shared__ float redM[4][32];
  __shared__ float redS[4][32];
  unsigned short* Kh = Ksm;
  unsigned short* Kl = Ksm + 8192;

  short8 ah[2][2], al[2][2];
  #pragma unroll
  for (int li = 0; li < 2; ++li)
    #pragma unroll
    for (int ks = 0; ks < 2; ++ks) {
      long qrow = ((long)b*LSEQ + lt*32 + li*16 + ln) * 64;
      ah[li][ks] = *(const short8*)&qh[qrow + ks*32 + g*8];
      al[li][ks] = *(const short8*)&ql[qrow + ks*32 + g*8];
    }

  const int rb = tid >> 3, jj = tid & 7;
  const int dst0 = rb*64 + ((jj ^ (rb & 7)) << 3);
  const long kbase = ((long)b*LSEQ + rb)*64 + jj*8;

  short8 rkh[4], rkl[4];
  #pragma unroll
  for (int j = 0; j < 4; ++j) {
    rkh[j] = *(const short8*)&kh[kbase + j*2048];
    rkl[j] = *(const short8*)&kl[kbase + j*2048];
  }

  f32x4 acc[8][2][2] = {};
  #pragma unroll
  for (int c = 0; c < 8; ++c) {
    __syncthreads();
    #pragma unroll
    for (int j = 0; j < 4; ++j) {
      *(short8*)&Kh[dst0 + j*2048] = rkh[j];
      *(short8*)&Kl[dst0 + j*2048] = rkl[j];
    }
    __syncthreads();
    if (c < 7) {
      #pragma unroll
      for (int j = 0; j < 4; ++j) {
        rkh[j] = *(const short8*)&kh[kbase + (long)(c+1)*8192 + j*2048];
        rkl[j] = *(const short8*)&kl[kbase + (long)(c+1)*8192 + j*2048];
      }
    }
    __builtin_amdgcn_s_setprio(1);
    #pragma unroll
    for (int fq = 0; fq < 2; ++fq) {
      int mloc = wave*32 + fq*16 + ln;
      #pragma unroll
      for (int ks = 0; ks < 2; ++ks) {
        int s = ((ks*4 + g) ^ (mloc & 7)) << 3;
        short8 bh = *(const short8*)&Kh[mloc*64 + s];
        short8 bl = *(const short8*)&Kl[mloc*64 + s];
        #pragma unroll
        for (int li = 0; li < 2; ++li) {
          acc[c][fq][li] = __builtin_amdgcn_mfma_f32_16x16x32_bf16(ah[li][ks], bh, acc[c][fq][li], 0,0,0);
          acc[c][fq][li] = __builtin_amdgcn_mfma_f32_16x16x32_bf16(ah[li][ks], bl, acc[c][fq][li], 0,0,0);
          acc[c][fq][li] = __builtin_amdgcn_mfma_f32_16x16x32_bf16(al[li][ks], bh, acc[c][fq][li], 0,0,0);
        }
      }
    }
    __builtin_amdgcn_s_setprio(0);
  }

  float mx[2][4];
  #pragma unroll
  for (int li = 0; li < 2; ++li)
    #pragma unroll
    for (int j = 0; j < 4; ++j) {
      float m = -1e30f;
      #pragma unroll
      for (int c = 0; c < 8; ++c)
        #pragma unroll
        for (int fq = 0; fq < 2; ++fq) m = fmaxf(m, acc[c][fq][li][j]);
      #pragma unroll
      for (int off = 1; off < 16; off <<= 1) m = fmaxf(m, __shfl_xor(m, off));
      mx[li][j] = m;
    }
  if (ln == 0) {
    #pragma unroll
    for (int li = 0; li < 2; ++li)
      #pragma unroll
      for (int j = 0; j < 4; ++j) redM[wave][li*16 + g*4 + j] = mx[li][j];
  }
  __syncthreads();
  #pragma unroll
  for (int li = 0; li < 2; ++li)
    #pragma unroll
    for (int j = 0; j < 4; ++j) {
      float m = redM[0][li*16 + g*4 + j];
      #pragma unroll
      for (int w = 1; w < 4; ++w) m = fmaxf(m, redM[w][li*16 + g*4 + j]);
      mx[li][j] = m;
    }
  float sm[2][4];
  #pragma unroll
  for (int li = 0; li < 2; ++li)
    #pragma unroll
    for (int j = 0; j < 4; ++j) {
      float s = 0.f;
      #pragma unroll
      for (int c = 0; c < 8; ++c)
        #pragma unroll
        for (int fq = 0; fq < 2; ++fq) {
          float p = __expf(acc[c][fq][li][j] - mx[li][j]);
          acc[c][fq][li][j] = p;
          s += p;
        }
      #pragma unroll
      for (int off = 1; off < 16; off <<= 1) s += __shfl_xor(s, off);
      sm[li][j] = s;
    }
  if (ln == 0) {
    #pragma unroll
    for (int li = 0; li < 2; ++li)
      #pragma unroll
      for (int j = 0; j < 4; ++j) redS[wave][li*16 + g*4 + j] = sm[li][j];
  }
  __syncthreads();
  #pragma unroll
  for (int li = 0; li < 2; ++li)
    #pragma unroll
    for (int j = 0; j < 4; ++j) {
      float s = redS[0][li*16 + g*4 + j];
      #pragma unroll
      for (int w = 1; w < 4; ++w) s += redS[w][li*16 + g*4 + j];
      sm[li][j] = 1.0f / s;
    }

  unsigned short* Pb = Ksm;              // [32][1032]
  __syncthreads();
  #pragma unroll
  for (int c = 0; c < 8; ++c)
    #pragma unroll
    for (int fq = 0; fq < 2; ++fq) {
      int m0 = c*128 + wave*32 + fq*16 + ln;
      #pragma unroll
      for (int li = 0; li < 2; ++li)
        #pragma unroll
        for (int j = 0; j < 4; ++j)
          Pb[(li*16 + g*4 + j)*1032 + m0] = bf16_rn(acc[c][fq][li][j] * sm[li][j]);
    }
  __syncthreads();
  #pragma unroll
  for (int u = 0; u < 16; ++u) {
    int cid = tid + u*256;
    int row = cid >> 7, col = (cid & 127) * 8;
    short8 v = *(const short8*)&Pb[row*1032 + col];
    long gro = ((long)b*LSEQ + lt*32 + row)*LSEQ + col;
    *(short8*)&pbuf[gro] = v;
    f32x4 f0, f1;
    #pragma unroll
    for (int i = 0; i < 4; ++i) {
      f0[i] = bf16_to_f32((unsigned short)v[i]);
      f1[i] = bf16_to_f32((unsigned short)v[i+4]);
    }
    *(f32x4*)&attn[gro] = f0;
    *(f32x4*)&attn[gro + 4] = f1;
  }
}

// ---------- Kernel 4: out = gamma * (V @ P^T) + x ----------
__global__ __launch_bounds__(512, 2) void pv_out(
    const unsigned short* __restrict__ vws,
    const unsigned short* __restrict__ pbuf,
    const float* __restrict__ x,
    const float* __restrict__ gamma,
    float* __restrict__ out)
{
  const int gi = blockIdx.x;
  const int b  = (gi & 7) + 8 * (gi >> 7);
  const int t  = (gi >> 3) & 15;
  const int lt = t >> 2, ct = t & 3;
  const int tid = threadIdx.x;
  const int w = tid >> 6, lane = tid & 63;
  const int wcq = w >> 2, wlq = w & 3;
  const int g = lane >> 4, ln = lane & 15;

  __shared__ char smem[49152];
  unsigned short* Vst = (unsigned short*)smem;            // [128][64] swz
  unsigned short* Pst = (unsigned short*)(smem + 16384);  // [256][64] swz

  const int vr = tid >> 2, vs0 = (tid & 3) * 2;
  const long vbase = ((long)b*C_IN + ct*128 + vr)*LSEQ + vs0*8;
  const int pr = tid >> 1, ps0 = (tid & 1) * 4;
  const long pbase = ((long)b*LSEQ + lt*256 + pr)*LSEQ + ps0*8;

  f32x4 acc[4][4] = {};
  short8 rv[2], rp[4];
  #pragma unroll
  for (int j = 0; j < 2; ++j) rv[j] = *(const short8*)&vws[vbase + j*8];
  #pragma unroll
  for (int j = 0; j < 4; ++j) rp[j] = *(const short8*)&pbuf[pbase + j*8];

  for (int mb = 0; mb < 16; ++mb) {
    __syncthreads();
    #pragma unroll
    for (int j = 0; j < 2; ++j)
      *(short8*)&Vst[vr*64 + (((vs0 + j) ^ (vr & 7)) << 3)] = rv[j];
    #pragma unroll
    for (int j = 0; j < 4; ++j)
      *(short8*)&Pst[pr*64 + (((ps0 + j) ^ (pr & 7)) << 3)] = rp[j];
    __syncthreads();
    if (mb < 15) {
      #pragma unroll
      for (int j = 0; j < 2; ++j) rv[j] = *(const short8*)&vws[vbase + (mb+1)*64 + j*8];
      #pragma unroll
      for (int j = 0; j < 4; ++j) rp[j] = *(const short8*)&pbuf[pbase + (mb+1)*64 + j*8];
    }
    __builtin_amdgcn_s_setprio(1);
    #pragma unroll
    for (int ks = 0; ks < 2; ++ks) {
      short8 bf[4];
      #pragma unroll
      for (int lf = 0; lf < 4; ++lf) {
        int prow = wlq*64 + lf*16 + ln;
        bf[lf] = *(const short8*)&Pst[prow*64 + (((ks*4 + g) ^ (prow & 7)) << 3)];
      }
      #pragma unroll
      for (int cf = 0; cf < 4; ++cf) {
        int cr = wcq*64 + cf*16 + ln;
        short8 af = *(const short8*)&Vst[cr*64 + (((ks*4 + g) ^ (cr & 7)) << 3)];
        #pragma unroll
        for (int lf = 0; lf < 4; ++lf)
          acc[cf][lf] = __builtin_amdgcn_mfma_f32_16x16x32_bf16(af, bf[lf], acc[cf][lf], 0,0,0);
      }
    }
    __builtin_amdgcn_s_setprio(0);
  }

  const float gm = gamma[0];
  #pragma unroll
  for (int cf = 0; cf < 4; ++cf)
    #pragma unroll
    for (int lf = 0; lf < 4; ++lf)
      #pragma unroll
      for (int j = 0; j < 4; ++j) {
        int c = ct*128 + wcq*64 + cf*16 + g*4 + j;
        int l = lt*256 + wlq*64 + lf*16 + ln;
        long o = ((long)b*C_IN + c)*LSEQ + l;
        out[o] = gm * acc[cf][lf][j] + x[o];
      }
}

extern "C" void kernel_launch(void* const* d_in, const int* in_sizes, int n_in,
                              void* d_out, int out_size, void* d_ws, size_t ws_size,
                              hipStream_t stream)
{
  const float* x  = (const float*)d_in[0];
  const float* Wq = (const float*)d_in[1];
  const float* bq = (const float*)d_in[2];
  const float* Wk = (const float*)d_in[3];
  const float* bk = (const float*)d_in[4];
  const float* Wv = (const float*)d_in[5];
  const float* bv = (const float*)d_in[6];
  const float* gamma = (const float*)d_in[7];
  float* out  = (float*)d_out;
  float* attn = out + OUT_ELEMS;

  char* ws = (char*)d_ws;
  unsigned short* Wqh = (unsigned short*)(ws + 0);
  unsigned short* Wql = (unsigned short*)(ws + 65536);
  unsigned short* Wkh = (unsigned short*)(ws + 131072);
  unsigned short* Wkl = (unsigned short*)(ws + 196608);
  unsigned short* Wvh = (unsigned short*)(ws + 262144);
  unsigned short* qhp = (unsigned short*)(ws + 786432);
  unsigned short* qlp = (unsigned short*)(ws + 786432 + 1ul*4194304);
  unsigned short* khp = (unsigned short*)(ws + 786432 + 2ul*4194304);
  unsigned short* klp = (unsigned short*)(ws + 786432 + 3ul*4194304);
  unsigned short* vws = (unsigned short*)(ws + 786432 + 4ul*4194304);
  unsigned short* pbuf = (unsigned short*)(ws + 786432 + 4ul*4194304 + 33554432);

  split_weights<<<320, 256, 0, stream>>>(Wq, Wk, Wv, Wqh, Wql, Wkh, Wkl, Wvh);
  proj<<<1536, 256, 0, stream>>>(x, Wqh, Wql, Wkh, Wkl, Wvh, bq, bk, bv, qhp, qlp, khp, klp, vws);
  energy_softmax<<<1024, 256, 0, stream>>>(qhp, qlp, khp, klp, attn, pbuf);
  pv_out<<<512, 512, 0, stream>>>(vws, pbuf, x, gamma, out);
}

// Round 14
// 170.155 us; speedup vs baseline: 1.4971x; 1.0336x over previous
//
#include <hip/hip_runtime.h>

typedef __attribute__((ext_vector_type(8))) short short8;
typedef __attribute__((ext_vector_type(4))) float f32x4;

#define B_SZ 32
#define C_IN 512
#define C8V 64
#define LSEQ 1024
#define OUT_ELEMS (B_SZ * C_IN * LSEQ)

__device__ inline unsigned short bf16_rn(float f) {
  unsigned int u = __float_as_uint(f);
  unsigned int r = 0x7FFFu + ((u >> 16) & 1u);
  return (unsigned short)((u + r) >> 16);
}
__device__ inline float bf16_to_f32(unsigned short h) {
  return __uint_as_float(((unsigned int)h) << 16);
}
__device__ inline void split_bf16(float f, unsigned short &hi, unsigned short &lo) {
  hi = bf16_rn(f);
  lo = bf16_rn(f - bf16_to_f32(hi));
}

// ---------- Kernel 0: pre-split weights into bf16 hi/lo planes ----------
__global__ __launch_bounds__(256) void split_weights(
    const float* __restrict__ Wq, const float* __restrict__ Wk, const float* __restrict__ Wv,
    unsigned short* __restrict__ Wqh, unsigned short* __restrict__ Wql,
    unsigned short* __restrict__ Wkh, unsigned short* __restrict__ Wkl,
    unsigned short* __restrict__ Wvh)
{
  int i = (blockIdx.x * 256 + threadIdx.x) * 4;
  if (i < 262144) {
    f32x4 f = *(const f32x4*)&Wv[i];
    #pragma unroll
    for (int j = 0; j < 4; ++j) Wvh[i + j] = bf16_rn(f[j]);
  } else if (i < 294912) {
    int k = i - 262144;
    f32x4 f = *(const f32x4*)&Wq[k];
    #pragma unroll
    for (int j = 0; j < 4; ++j) { unsigned short h, l; split_bf16(f[j], h, l); Wqh[k+j] = h; Wql[k+j] = l; }
  } else {
    int k = i - 294912;
    f32x4 f = *(const f32x4*)&Wk[k];
    #pragma unroll
    for (int j = 0; j < 4; ++j) { unsigned short h, l; split_bf16(f[j], h, l); Wkh[k+j] = h; Wkl[k+j] = l; }
  }
}

// ---------- Kernel 1 (merged): q,k projection (blocks 0..511) + v projection (512..1535) ----------
__global__ __launch_bounds__(256, 2) void proj(
    const float* __restrict__ x,
    const unsigned short* __restrict__ Wqh, const unsigned short* __restrict__ Wql,
    const unsigned short* __restrict__ Wkh, const unsigned short* __restrict__ Wkl,
    const unsigned short* __restrict__ Wvh,
    const float* __restrict__ bq, const float* __restrict__ bk,
    const float* __restrict__ bv,
    unsigned short* __restrict__ qh, unsigned short* __restrict__ ql,
    unsigned short* __restrict__ kh, unsigned short* __restrict__ kl,
    unsigned short* __restrict__ vws)
{
  __shared__ char smem[49152];
  const int tid = threadIdx.x;
  const int wave = tid >> 6, lane = tid & 63;
  const int wr = wave >> 1, wc = wave & 1;
  const int g = lane >> 4, ln = lane & 15;

  if (blockIdx.x < 512) {
    // ================= q,k projection: tile M=128(64q+64k) x N=64 l =================
    const int gi = blockIdx.x;
    const int b  = (gi & 7) + 8 * (gi >> 7);
    const int nt = (gi >> 3) & 15;

    unsigned short* Ah = (unsigned short*)smem;      // [128][64] swz
    unsigned short* Al = Ah + 8192;
    unsigned short* Bh = Al + 8192;                  // [64][64] swz
    unsigned short* Bl = Bh + 4096;

    const int rb = tid >> 3, jj = tid & 7;
    const int adst0 = rb*64 + ((jj ^ (rb & 7)) << 3);
    const int xl = tid & 63, xkg = (tid >> 6) * 16;
    const long xcol = (long)b*C_IN*LSEQ + (long)nt*64 + xl;

    short8 rAh[4], rAl[4];
    float xv[16];
    rAh[0] = *(const short8*)&Wqh[rb*C_IN + jj*8];
    rAh[1] = *(const short8*)&Wqh[(rb+32)*C_IN + jj*8];
    rAh[2] = *(const short8*)&Wkh[rb*C_IN + jj*8];
    rAh[3] = *(const short8*)&Wkh[(rb+32)*C_IN + jj*8];
    rAl[0] = *(const short8*)&Wql[rb*C_IN + jj*8];
    rAl[1] = *(const short8*)&Wql[(rb+32)*C_IN + jj*8];
    rAl[2] = *(const short8*)&Wkl[rb*C_IN + jj*8];
    rAl[3] = *(const short8*)&Wkl[(rb+32)*C_IN + jj*8];
    #pragma unroll
    for (int i = 0; i < 16; ++i) xv[i] = x[xcol + (long)(xkg + i)*LSEQ];

    f32x4 acc[4][2] = {};

    for (int kb = 0; kb < 8; ++kb) {
      __syncthreads();
      #pragma unroll
      for (int j = 0; j < 4; ++j) {
        *(short8*)&Ah[adst0 + j*2048] = rAh[j];
        *(short8*)&Al[adst0 + j*2048] = rAl[j];
      }
      {
        unsigned short hb[16], lb[16];
        #pragma unroll
        for (int i = 0; i < 16; ++i) split_bf16(xv[i], hb[i], lb[i]);
        #pragma unroll
        for (int s2 = 0; s2 < 2; ++s2) {
          int d = xl*64 + ((((xkg >> 3) + s2) ^ (xl & 7)) << 3);
          *(short8*)&Bh[d] = *(const short8*)&hb[s2*8];
          *(short8*)&Bl[d] = *(const short8*)&lb[s2*8];
        }
      }
      // issue next-tile loads BEFORE the barrier: latency hides under barrier + MFMA
      if (kb < 7) {
        int ko = (kb+1)*64;
        rAh[0] = *(const short8*)&Wqh[rb*C_IN + ko + jj*8];
        rAh[1] = *(const short8*)&Wqh[(rb+32)*C_IN + ko + jj*8];
        rAh[2] = *(const short8*)&Wkh[rb*C_IN + ko + jj*8];
        rAh[3] = *(const short8*)&Wkh[(rb+32)*C_IN + ko + jj*8];
        rAl[0] = *(const short8*)&Wql[rb*C_IN + ko + jj*8];
        rAl[1] = *(const short8*)&Wql[(rb+32)*C_IN + ko + jj*8];
        rAl[2] = *(const short8*)&Wkl[rb*C_IN + ko + jj*8];
        rAl[3] = *(const short8*)&Wkl[(rb+32)*C_IN + ko + jj*8];
        #pragma unroll
        for (int i = 0; i < 16; ++i) xv[i] = x[xcol + (long)(ko + xkg + i)*LSEQ];
      }
      __syncthreads();
      __builtin_amdgcn_s_setprio(1);
      #pragma unroll
      for (int ks = 0; ks < 2; ++ks) {
        short8 bhf[2], blf[2];
        #pragma unroll
        for (int ni = 0; ni < 2; ++ni) {
          int cr = wc*32 + ni*16 + ln;
          int s = ((ks*4 + g) ^ (cr & 7)) << 3;
          bhf[ni] = *(const short8*)&Bh[cr*64 + s];
          blf[ni] = *(const short8*)&Bl[cr*64 + s];
        }
        #pragma unroll
        for (int mi = 0; mi < 4; ++mi) {
          int ar = wr*64 + mi*16 + ln;
          int s = ((ks*4 + g) ^ (ar & 7)) << 3;
          short8 ahf = *(const short8*)&Ah[ar*64 + s];
          short8 alf = *(const short8*)&Al[ar*64 + s];
          #pragma unroll
          for (int ni = 0; ni < 2; ++ni) {
            acc[mi][ni] = __builtin_amdgcn_mfma_f32_16x16x32_bf16(ahf, bhf[ni], acc[mi][ni], 0,0,0);
            acc[mi][ni] = __builtin_amdgcn_mfma_f32_16x16x32_bf16(ahf, blf[ni], acc[mi][ni], 0,0,0);
            acc[mi][ni] = __builtin_amdgcn_mfma_f32_16x16x32_bf16(alf, bhf[ni], acc[mi][ni], 0,0,0);
          }
        }
      }
      __builtin_amdgcn_s_setprio(0);
    }
    __syncthreads();
    unsigned short* Trh = (unsigned short*)smem;     // [64 l][136]
    unsigned short* Trl = Trh + 64*136;
    #pragma unroll
    for (int mi = 0; mi < 4; ++mi)
      #pragma unroll
      for (int ni = 0; ni < 2; ++ni)
        #pragma unroll
        for (int j = 0; j < 4; ++j) {
          int rloc = wr*64 + mi*16 + g*4 + j;
          int cloc = wc*32 + ni*16 + ln;
          float bias = (rloc < 64) ? bq[rloc] : bk[rloc - 64];
          unsigned short hi, lo; split_bf16(acc[mi][ni][j] + bias, hi, lo);
          Trh[cloc*136 + rloc] = hi;
          Trl[cloc*136 + rloc] = lo;
        }
    __syncthreads();
    #pragma unroll
    for (int i = 0; i < 4; ++i) {
      int idx = tid + i*256;
      int l = idx >> 4, s = idx & 15;
      long row = ((long)b*LSEQ + nt*64 + l) * 64;
      short8 h  = *(const short8*)&Trh[l*136 + s*8];
      short8 lo = *(const short8*)&Trl[l*136 + s*8];
      if (s < 8) { *(short8*)&qh[row + s*8] = h;      *(short8*)&ql[row + s*8] = lo; }
      else       { *(short8*)&kh[row + (s-8)*8] = h;  *(short8*)&kl[row + (s-8)*8] = lo; }
    }
  } else {
    // ================= v projection: tile 128c x 128l =================
    const int gj = blockIdx.x - 512;
    const int b  = (gj & 7) + 8 * (gj >> 8);
    const int t  = (gj >> 3) & 31;
    const int lt = t & 7, ct = t >> 3;

    unsigned short* Ahs = (unsigned short*)smem;     // [128][64] swz
    unsigned short* Bhs = Ahs + 8192;                // [128][64] swz

    const int rb = tid >> 3, jj = tid & 7;
    const int adst0 = rb*64 + ((jj ^ (rb & 7)) << 3);
    const long wbase = (long)(ct*128 + rb)*C_IN + jj*8;
    const int xl = tid & 127, xkg = (tid >> 7) * 32;
    const long xcol = (long)b*C_IN*LSEQ + (long)lt*128 + xl;

    short8 rA[4];
    float xv[32];
    #pragma unroll
    for (int j = 0; j < 4; ++j) rA[j] = *(const short8*)&Wvh[wbase + (long)j*32*C_IN];
    #pragma unroll
    for (int i = 0; i < 32; ++i) xv[i] = x[xcol + (long)(xkg + i)*LSEQ];

    f32x4 acc[4][4] = {};

    for (int kb = 0; kb < 8; ++kb) {
      __syncthreads();
      #pragma unroll
      for (int j = 0; j < 4; ++j)
        *(short8*)&Ahs[adst0 + j*2048] = rA[j];
      {
        unsigned short hb[32];
        #pragma unroll
        for (int i = 0; i < 32; ++i) hb[i] = bf16_rn(xv[i]);
        #pragma unroll
        for (int s2 = 0; s2 < 4; ++s2) {
          int d = xl*64 + ((((xkg >> 3) + s2) ^ (xl & 7)) << 3);
          *(short8*)&Bhs[d] = *(const short8*)&hb[s2*8];
        }
      }
      // issue next-tile loads BEFORE the barrier
      if (kb < 7) {
        int ko = (kb+1)*64;
        #pragma unroll
        for (int j = 0; j < 4; ++j) rA[j] = *(const short8*)&Wvh[wbase + (long)j*32*C_IN + ko];
        #pragma unroll
        for (int i = 0; i < 32; ++i) xv[i] = x[xcol + (long)(ko + xkg + i)*LSEQ];
      }
      __syncthreads();
      __builtin_amdgcn_s_setprio(1);
      #pragma unroll
      for (int ks = 0; ks < 2; ++ks) {
        short8 bf[4];
        #pragma unroll
        for (int ni = 0; ni < 4; ++ni) {
          int cr = wc*64 + ni*16 + ln;
          bf[ni] = *(const short8*)&Bhs[cr*64 + (((ks*4 + g) ^ (cr & 7)) << 3)];
        }
        #pragma unroll
        for (int mi = 0; mi < 4; ++mi) {
          int ar = wr*64 + mi*16 + ln;
          short8 af = *(const short8*)&Ahs[ar*64 + (((ks*4 + g) ^ (ar & 7)) << 3)];
          #pragma unroll
          for (int ni = 0; ni < 4; ++ni)
            acc[mi][ni] = __builtin_amdgcn_mfma_f32_16x16x32_bf16(af, bf[ni], acc[mi][ni], 0,0,0);
        }
      }
      __builtin_amdgcn_s_setprio(0);
    }
    __syncthreads();
    unsigned short* Tr = (unsigned short*)smem;      // [128 c][136]
    #pragma unroll
    for (int mi = 0; mi < 4; ++mi)
      #pragma unroll
      for (int ni = 0; ni < 4; ++ni)
        #pragma unroll
        for (int j = 0; j < 4; ++j) {
          int rloc = wr*64 + mi*16 + g*4 + j;
          int cloc = wc*64 + ni*16 + ln;
          Tr[rloc*136 + cloc] = bf16_rn(acc[mi][ni][j] + bv[ct*128 + rloc]);
        }
    __syncthreads();
    #pragma unroll
    for (int i = 0; i < 8; ++i) {
      int idx = tid + i*256;
      int c = idx >> 4, s = idx & 15;
      *(short8*)&vws[((long)b*C_IN + ct*128 + c)*LSEQ + lt*128 + s*8] =
        *(const short8*)&Tr[c*136 + s*8];
    }
  }
}

// ---------- Kernel 3: energy + softmax -> attn f32 (d_out) + P bf16 copy ----------
// 32 rows/block; linear grid 1024, XCD-swizzled: 32 blocks of b on XCD b%8.
__global__ __launch_bounds__(256, 2) void energy_softmax(
    const unsigned short* __restrict__ qh, const unsigned short* __restrict__ ql,
    const unsigned short* __restrict__ kh, const unsigned short* __restrict__ kl,
    float* __restrict__ attn, unsigned short* __restrict__ pbuf)
{
  const int gi = blockIdx.x;
  const int b  = (gi & 7) + 8 * (gi >> 8);
  const int lt = (gi >> 3) & 31;
  const int tid = threadIdx.x;
  const int wave = tid >> 6, lane = tid & 63;
  const int g = lane >> 4, ln = lane & 15;

  __shared__ unsigned short Ksm[33024];   // K: hi[8192]+lo[8192]; reused as Pb[32][1032]
  __shared__ float redM[4][32];
  __shared__ float redS[4][32];
  unsigned short* Kh = Ksm;
  unsigned short* Kl = Ksm + 8192;

  short8 ah[2][2], al[2][2];
  #pragma unroll
  for (int li = 0; li < 2; ++li)
    #pragma unroll
    for (int ks = 0; ks < 2; ++ks) {
      long qrow = ((long)b*LSEQ + lt*32 + li*16 + ln) * 64;
      ah[li][ks] = *(const short8*)&qh[qrow + ks*32 + g*8];
      al[li][ks] = *(const short8*)&ql[qrow + ks*32 + g*8];
    }

  const int rb = tid >> 3, jj = tid & 7;
  const int dst0 = rb*64 + ((jj ^ (rb & 7)) << 3);
  const long kbase = ((long)b*LSEQ + rb)*64 + jj*8;

  short8 rkh[4], rkl[4];
  #pragma unroll
  for (int j = 0; j < 4; ++j) {
    rkh[j] = *(const short8*)&kh[kbase + j*2048];
    rkl[j] = *(const short8*)&kl[kbase + j*2048];
  }

  f32x4 acc[8][2][2] = {};
  #pragma unroll
  for (int c = 0; c < 8; ++c) {
    __syncthreads();
    #pragma unroll
    for (int j = 0; j < 4; ++j) {
      *(short8*)&Kh[dst0 + j*2048] = rkh[j];
      *(short8*)&Kl[dst0 + j*2048] = rkl[j];
    }
    // issue next-chunk loads BEFORE the barrier
    if (c < 7) {
      #pragma unroll
      for (int j = 0; j < 4; ++j) {
        rkh[j] = *(const short8*)&kh[kbase + (long)(c+1)*8192 + j*2048];
        rkl[j] = *(const short8*)&kl[kbase + (long)(c+1)*8192 + j*2048];
      }
    }
    __syncthreads();
    __builtin_amdgcn_s_setprio(1);
    #pragma unroll
    for (int fq = 0; fq < 2; ++fq) {
      int mloc = wave*32 + fq*16 + ln;
      #pragma unroll
      for (int ks = 0; ks < 2; ++ks) {
        int s = ((ks*4 + g) ^ (mloc & 7)) << 3;
        short8 bh = *(const short8*)&Kh[mloc*64 + s];
        short8 bl = *(const short8*)&Kl[mloc*64 + s];
        #pragma unroll
        for (int li = 0; li < 2; ++li) {
          acc[c][fq][li] = __builtin_amdgcn_mfma_f32_16x16x32_bf16(ah[li][ks], bh, acc[c][fq][li], 0,0,0);
          acc[c][fq][li] = __builtin_amdgcn_mfma_f32_16x16x32_bf16(ah[li][ks], bl, acc[c][fq][li], 0,0,0);
          acc[c][fq][li] = __builtin_amdgcn_mfma_f32_16x16x32_bf16(al[li][ks], bh, acc[c][fq][li], 0,0,0);
        }
      }
    }
    __builtin_amdgcn_s_setprio(0);
  }

  float mx[2][4];
  #pragma unroll
  for (int li = 0; li < 2; ++li)
    #pragma unroll
    for (int j = 0; j < 4; ++j) {
      float m = -1e30f;
      #pragma unroll
      for (int c = 0; c < 8; ++c)
        #pragma unroll
        for (int fq = 0; fq < 2; ++fq) m = fmaxf(m, acc[c][fq][li][j]);
      #pragma unroll
      for (int off = 1; off < 16; off <<= 1) m = fmaxf(m, __shfl_xor(m, off));
      mx[li][j] = m;
    }
  if (ln == 0) {
    #pragma unroll
    for (int li = 0; li < 2; ++li)
      #pragma unroll
      for (int j = 0; j < 4; ++j) redM[wave][li*16 + g*4 + j] = mx[li][j];
  }
  __syncthreads();
  #pragma unroll
  for (int li = 0; li < 2; ++li)
    #pragma unroll
    for (int j = 0; j < 4; ++j) {
      float m = redM[0][li*16 + g*4 + j];
      #pragma unroll
      for (int w = 1; w < 4; ++w) m = fmaxf(m, redM[w][li*16 + g*4 + j]);
      mx[li][j] = m;
    }
  float sm[2][4];
  #pragma unroll
  for (int li = 0; li < 2; ++li)
    #pragma unroll
    for (int j = 0; j < 4; ++j) {
      float s = 0.f;
      #pragma unroll
      for (int c = 0; c < 8; ++c)
        #pragma unroll
        for (int fq = 0; fq < 2; ++fq) {
          float p = __expf(acc[c][fq][li][j] - mx[li][j]);
          acc[c][fq][li][j] = p;
          s += p;
        }
      #pragma unroll
      for (int off = 1; off < 16; off <<= 1) s += __shfl_xor(s, off);
      sm[li][j] = s;
    }
  if (ln == 0) {
    #pragma unroll
    for (int li = 0; li < 2; ++li)
      #pragma unroll
      for (int j = 0; j < 4; ++j) redS[wave][li*16 + g*4 + j] = sm[li][j];
  }
  __syncthreads();
  #pragma unroll
  for (int li = 0; li < 2; ++li)
    #pragma unroll
    for (int j = 0; j < 4; ++j) {
      float s = redS[0][li*16 + g*4 + j];
      #pragma unroll
      for (int w = 1; w < 4; ++w) s += redS[w][li*16 + g*4 + j];
      sm[li][j] = 1.0f / s;
    }

  unsigned short* Pb = Ksm;              // [32][1032]
  __syncthreads();
  #pragma unroll
  for (int c = 0; c < 8; ++c)
    #pragma unroll
    for (int fq = 0; fq < 2; ++fq) {
      int m0 = c*128 + wave*32 + fq*16 + ln;
      #pragma unroll
      for (int li = 0; li < 2; ++li)
        #pragma unroll
        for (int j = 0; j < 4; ++j)
          Pb[(li*16 + g*4 + j)*1032 + m0] = bf16_rn(acc[c][fq][li][j] * sm[li][j]);
    }
  __syncthreads();
  #pragma unroll
  for (int u = 0; u < 16; ++u) {
    int cid = tid + u*256;
    int row = cid >> 7, col = (cid & 127) * 8;
    short8 v = *(const short8*)&Pb[row*1032 + col];
    long gro = ((long)b*LSEQ + lt*32 + row)*LSEQ + col;
    *(short8*)&pbuf[gro] = v;
    f32x4 f0, f1;
    #pragma unroll
    for (int i = 0; i < 4; ++i) {
      f0[i] = bf16_to_f32((unsigned short)v[i]);
      f1[i] = bf16_to_f32((unsigned short)v[i+4]);
    }
    *(f32x4*)&attn[gro] = f0;
    *(f32x4*)&attn[gro + 4] = f1;
  }
}

// ---------- Kernel 4: out = gamma * (V @ P^T) + x ----------
__global__ __launch_bounds__(512, 2) void pv_out(
    const unsigned short* __restrict__ vws,
    const unsigned short* __restrict__ pbuf,
    const float* __restrict__ x,
    const float* __restrict__ gamma,
    float* __restrict__ out)
{
  const int gi = blockIdx.x;
  const int b  = (gi & 7) + 8 * (gi >> 7);
  const int t  = (gi >> 3) & 15;
  const int lt = t >> 2, ct = t & 3;
  const int tid = threadIdx.x;
  const int w = tid >> 6, lane = tid & 63;
  const int wcq = w >> 2, wlq = w & 3;
  const int g = lane >> 4, ln = lane & 15;

  __shared__ char smem[49152];
  unsigned short* Vst = (unsigned short*)smem;            // [128][64] swz
  unsigned short* Pst = (unsigned short*)(smem + 16384);  // [256][64] swz

  const int vr = tid >> 2, vs0 = (tid & 3) * 2;
  const long vbase = ((long)b*C_IN + ct*128 + vr)*LSEQ + vs0*8;
  const int pr = tid >> 1, ps0 = (tid & 1) * 4;
  const long pbase = ((long)b*LSEQ + lt*256 + pr)*LSEQ + ps0*8;

  f32x4 acc[4][4] = {};
  short8 rv[2], rp[4];
  #pragma unroll
  for (int j = 0; j < 2; ++j) rv[j] = *(const short8*)&vws[vbase + j*8];
  #pragma unroll
  for (int j = 0; j < 4; ++j) rp[j] = *(const short8*)&pbuf[pbase + j*8];

  for (int mb = 0; mb < 16; ++mb) {
    __syncthreads();
    #pragma unroll
    for (int j = 0; j < 2; ++j)
      *(short8*)&Vst[vr*64 + (((vs0 + j) ^ (vr & 7)) << 3)] = rv[j];
    #pragma unroll
    for (int j = 0; j < 4; ++j)
      *(short8*)&Pst[pr*64 + (((ps0 + j) ^ (pr & 7)) << 3)] = rp[j];
    // issue next-tile loads BEFORE the barrier
    if (mb < 15) {
      #pragma unroll
      for (int j = 0; j < 2; ++j) rv[j] = *(const short8*)&vws[vbase + (mb+1)*64 + j*8];
      #pragma unroll
      for (int j = 0; j < 4; ++j) rp[j] = *(const short8*)&pbuf[pbase + (mb+1)*64 + j*8];
    }
    __syncthreads();
    __builtin_amdgcn_s_setprio(1);
    #pragma unroll
    for (int ks = 0; ks < 2; ++ks) {
      short8 bf[4];
      #pragma unroll
      for (int lf = 0; lf < 4; ++lf) {
        int prow = wlq*64 + lf*16 + ln;
        bf[lf] = *(const short8*)&Pst[prow*64 + (((ks*4 + g) ^ (prow & 7)) << 3)];
      }
      #pragma unroll
      for (int cf = 0; cf < 4; ++cf) {
        int cr = wcq*64 + cf*16 + ln;
        short8 af = *(const short8*)&Vst[cr*64 + (((ks*4 + g) ^ (cr & 7)) << 3)];
        #pragma unroll
        for (int lf = 0; lf < 4; ++lf)
          acc[cf][lf] = __builtin_amdgcn_mfma_f32_16x16x32_bf16(af, bf[lf], acc[cf][lf], 0,0,0);
      }
    }
    __builtin_amdgcn_s_setprio(0);
  }

  const float gm = gamma[0];
  #pragma unroll
  for (int cf = 0; cf < 4; ++cf)
    #pragma unroll
    for (int lf = 0; lf < 4; ++lf)
      #pragma unroll
      for (int j = 0; j < 4; ++j) {
        int c = ct*128 + wcq*64 + cf*16 + g*4 + j;
        int l = lt*256 + wlq*64 + lf*16 + ln;
        long o = ((long)b*C_IN + c)*LSEQ + l;
        out[o] = gm * acc[cf][lf][j] + x[o];
      }
}

extern "C" void kernel_launch(void* const* d_in, const int* in_sizes, int n_in,
                              void* d_out, int out_size, void* d_ws, size_t ws_size,
                              hipStream_t stream)
{
  const float* x  = (const float*)d_in[0];
  const float* Wq = (const float*)d_in[1];
  const float* bq = (const float*)d_in[2];
  const float* Wk = (const float*)d_in[3];
  const float* bk = (const float*)d_in[4];
  const float* Wv = (const float*)d_in[5];
  const float* bv = (const float*)d_in[6];
  const float* gamma = (const float*)d_in[7];
  float* out  = (float*)d_out;
  float* attn = out + OUT_ELEMS;

  char* ws = (char*)d_ws;
  unsigned short* Wqh = (unsigned short*)(ws + 0);
  unsigned short* Wql = (unsigned short*)(ws + 65536);
  unsigned short* Wkh = (unsigned short*)(ws + 131072);
  unsigned short* Wkl = (unsigned short*)(ws + 196608);
  unsigned short* Wvh = (unsigned short*)(ws + 262144);
  unsigned short* qhp = (unsigned short*)(ws + 786432);
  unsigned short* qlp = (unsigned short*)(ws + 786432 + 1ul*4194304);
  unsigned short* khp = (unsigned short*)(ws + 786432 + 2ul*4194304);
  unsigned short* klp = (unsigned short*)(ws + 786432 + 3ul*4194304);
  unsigned short* vws = (unsigned short*)(ws + 786432 + 4ul*4194304);
  unsigned short* pbuf = (unsigned short*)(ws + 786432 + 4ul*4194304 + 33554432);

  split_weights<<<320, 256, 0, stream>>>(Wq, Wk, Wv, Wqh, Wql, Wkh, Wkl, Wvh);
  proj<<<1536, 256, 0, stream>>>(x, Wqh, Wql, Wkh, Wkl, Wvh, bq, bk, bv, qhp, qlp, khp, klp, vws);
  energy_softmax<<<1024, 256, 0, stream>>>(qhp, qlp, khp, klp, attn, pbuf);
  pv_out<<<512, 512, 0, stream>>>(vws, pbuf, x, gamma, out);
}